// Round 5
// baseline (252.549 us; speedup 1.0000x reference)
//
#include <hip/hip_runtime.h>

typedef unsigned short u16;
typedef unsigned int u32;
typedef __attribute__((ext_vector_type(8))) short bf16x8;
typedef __attribute__((ext_vector_type(4))) float f32x4;

__device__ __forceinline__ u16 f2bf(float x) {
  unsigned u = __float_as_uint(x);
  u += 0x7fffu + ((u >> 16) & 1u);   // RNE
  return (u16)(u >> 16);
}
__device__ __forceinline__ float bf2f(u16 z) {
  return __uint_as_float((u32)z << 16);
}

// ---------------- cast fp32 -> bf16 (RNE); n divisible by 1024 ----------------
__global__ __launch_bounds__(256) void cast_kernel(const float* __restrict__ in,
                                                   u16* __restrict__ out, int n) {
  int i = (blockIdx.x * 256 + threadIdx.x) * 4;
  if (i >= n) return;
  float4 f = *(const float4*)(in + i);
  ushort4 o;
  o.x = f2bf(f.x); o.y = f2bf(f.y); o.z = f2bf(f.z); o.w = f2bf(f.w);
  *(ushort4*)(out + i) = o;
}

// ------------- transpose+cast 4 weights: W[k][n] fp32 -> Wt[n][k] bf16 -------------
__global__ __launch_bounds__(256) void transcast(const float* __restrict__ W0,
                                                 const float* __restrict__ W1,
                                                 const float* __restrict__ W2,
                                                 const float* __restrict__ W3,
                                                 u16* __restrict__ out) {
  __shared__ alignas(16) u16 ls[64 * 72];
  int z = blockIdx.z;
  const float* W = (z == 0) ? W0 : (z == 1) ? W1 : (z == 2) ? W2 : W3;
  u16* o = out + (size_t)z * (1024u * 1024u);
  int kt = blockIdx.y * 64, nt = blockIdx.x * 64;
  int tid = threadIdx.x;
  int r = tid >> 2, c0 = (tid & 3) * 16;
  const float* src = W + (size_t)(kt + r) * 1024 + nt + c0;
  u16 tmp[16];
#pragma unroll
  for (int c = 0; c < 16; c += 4) {
    float4 f = *(const float4*)(src + c);
    tmp[c + 0] = f2bf(f.x); tmp[c + 1] = f2bf(f.y);
    tmp[c + 2] = f2bf(f.z); tmp[c + 3] = f2bf(f.w);
  }
#pragma unroll
  for (int c = 0; c < 16; ++c) ls[r * 72 + c0 + c] = tmp[c];
  __syncthreads();
#pragma unroll
  for (int pass = 0; pass < 4; ++pass) {
    int n = pass * 16 + (tid >> 4);
    int kk = (tid & 15) * 4;
    ushort4 val;
    val.x = ls[(kk + 0) * 72 + n];
    val.y = ls[(kk + 1) * 72 + n];
    val.z = ls[(kk + 2) * 72 + n];
    val.w = ls[(kk + 3) * 72 + n];
    *(ushort4*)(o + (size_t)(nt + n) * 1024 + kt + kk) = val;
  }
}

// ------- bf16 MFMA GEMM 128x128, BK=64, split-K=2: partial bf16 out -------
// grid.z: proj = z>>1 selects B (stride bz); kh = z&1. Cz = C + z*cz (bf16).
#define GLD 72  // 144B row stride: b128 frag reads hit 8 even bank-groups (free)
__global__ __launch_bounds__(256, 3) void gemm128(const u16* __restrict__ A,
                                                  const u16* __restrict__ Bmat,
                                                  u16* __restrict__ C,
                                                  int K, size_t bz, size_t cz) {
  __shared__ alignas(16) u16 As[128 * GLD];
  __shared__ alignas(16) u16 Bs[128 * GLD];
  int z = blockIdx.z;
  const u16* B = Bmat + (size_t)(z >> 1) * bz;
  u16* Cz = C + (size_t)z * cz;
  int kbeg = (z & 1) * 512;
  int tid = threadIdx.x;
  int bm = blockIdx.y * 128, bn = blockIdx.x * 128;
  int lane = tid & 63, w = tid >> 6;
  int wm = (w >> 1) * 64, wn = (w & 1) * 64;
  int m16 = lane & 15, q = lane >> 4;
  f32x4 acc[4][4] = {};
  int srow = tid >> 1, scol = (tid & 1) * 32;
  const u16* aptr = A + (size_t)(bm + srow) * K + scol;
  const u16* bptr = B + (size_t)(bn + srow) * K + scol;
  for (int k0 = kbeg; k0 < kbeg + 512; k0 += 64) {
    uint4 a[4], b[4];
#pragma unroll
    for (int j = 0; j < 4; ++j) {
      a[j] = *(const uint4*)(aptr + k0 + j * 8);
      b[j] = *(const uint4*)(bptr + k0 + j * 8);
    }
    __syncthreads();
#pragma unroll
    for (int j = 0; j < 4; ++j) {
      *(uint4*)&As[srow * GLD + scol + j * 8] = a[j];
      *(uint4*)&Bs[srow * GLD + scol + j * 8] = b[j];
    }
    __syncthreads();
#pragma unroll
    for (int s = 0; s < 2; ++s) {
      bf16x8 af[4], bfr[4];
#pragma unroll
      for (int mt = 0; mt < 4; ++mt)
        af[mt] = *(const bf16x8*)&As[(wm + mt * 16 + m16) * GLD + s * 32 + q * 8];
#pragma unroll
      for (int nt = 0; nt < 4; ++nt)
        bfr[nt] = *(const bf16x8*)&Bs[(wn + nt * 16 + m16) * GLD + s * 32 + q * 8];
#pragma unroll
      for (int mt = 0; mt < 4; ++mt)
#pragma unroll
        for (int nt = 0; nt < 4; ++nt)
          acc[mt][nt] = __builtin_amdgcn_mfma_f32_16x16x32_bf16(af[mt], bfr[nt], acc[mt][nt], 0, 0, 0);
    }
  }
#pragma unroll
  for (int mt = 0; mt < 4; ++mt)
#pragma unroll
    for (int nt = 0; nt < 4; ++nt)
#pragma unroll
      for (int r = 0; r < 4; ++r) {
        int row = bm + wm + mt * 16 + q * 4 + r;
        int col = bn + wn + nt * 16 + m16;
        Cz[(size_t)row * 1024 + col] = f2bf(acc[mt][nt][r]);
      }
}

// ---- out = bf(p0) + bf(p1) (o-proj split-K reduce) -> fp32, 8 elems/thread ----
__global__ __launch_bounds__(256) void addout(const u16* __restrict__ p0,
                                              const u16* __restrict__ p1,
                                              float* __restrict__ out, int n) {
  int i = (blockIdx.x * 256 + threadIdx.x) * 8;
  if (i >= n) return;
  u16 a[8], b[8];
  *(uint4*)a = *(const uint4*)(p0 + i);
  *(uint4*)b = *(const uint4*)(p1 + i);
  float o[8];
#pragma unroll
  for (int j = 0; j < 8; ++j) o[j] = bf2f(a[j]) + bf2f(b[j]);
  *(float4*)(out + i) = *(float4*)&o[0];
  *(float4*)(out + i + 4) = *(float4*)&o[4];
}

// -- fused: y=0 -> q normrope, y=1 -> k normrope, y=2 -> v transpose --
// all read (bf16 partial0 + partial1); p has 6 partials at stride PS.
#define PS ((size_t)2048 * 1024)
__global__ __launch_bounds__(256) void nrv(const u16* __restrict__ p,
                                           u16* __restrict__ qd,
                                           u16* __restrict__ kd,
                                           u16* __restrict__ vt,
                                           const float* __restrict__ s_qk) {
  int tid = threadIdx.x;
  int y = blockIdx.y;
  if (y < 2) {   // ---- normrope on q (y=0) / k (y=1) ----
    const u16* a = p + (size_t)(2 * y) * PS;
    const u16* b = a + PS;
    u16* dst = y ? kd : qd;
    int lane = tid & 63;
    int idx = blockIdx.x * 4 + (tid >> 6);   // t*16 + h
    int t = idx >> 4, h = idx & 15;
    size_t off = (size_t)t * 1024 + h * 64 + lane;
    float x = bf2f(a[off]) + bf2f(b[off]);
    float ss = x * x;
#pragma unroll
    for (int m = 32; m; m >>= 1) ss += __shfl_xor(ss, m);
    float xn = x * rsqrtf(ss + 1e-12f) * (s_qk[h * 64 + lane] * 32.0f);  // sqrt(1024)=32
    float other = __shfl_xor(xn, 32);
    int i = lane & 31;
    float fr = (i < 16) ? exp2f(-10.0f * (float)i / 15.0f) : 0.0f;  // (1/1024)^(i/15)
    float th = (float)t * fr;
    float c = cosf(th), s = sinf(th);
    float sgn = (lane < 32) ? s : -s;  // y1 = x1*c + x2*s ; y2 = x2*c - x1*s
    dst[off] = f2bf(xn * c + other * sgn);
    return;
  }
  // ---- v transpose: vt[h*64+d][t] = bf(v0+v1) ----
  if (blockIdx.x >= 512) return;
  __shared__ alignas(16) u16 ls[64 * 72];
  const u16* v0 = p + 4 * PS;
  const u16* v1 = p + 5 * PS;
  int t0 = (blockIdx.x & 31) * 64, h = blockIdx.x >> 5;
  int r = tid >> 2, c0 = (tid & 3) * 16;
  size_t off = (size_t)(t0 + r) * 1024 + h * 64 + c0;
  u16 ta[16], tb[16];
  *(uint4*)&ta[0] = *(const uint4*)(v0 + off);
  *(uint4*)&ta[8] = *(const uint4*)(v0 + off + 8);
  *(uint4*)&tb[0] = *(const uint4*)(v1 + off);
  *(uint4*)&tb[8] = *(const uint4*)(v1 + off + 8);
#pragma unroll
  for (int c = 0; c < 16; ++c) ls[r * 72 + c0 + c] = f2bf(bf2f(ta[c]) + bf2f(tb[c]));
  __syncthreads();
#pragma unroll
  for (int pass = 0; pass < 4; ++pass) {
    int n = pass * 16 + (tid >> 4);   // d within head
    int kk = (tid & 15) * 4;          // t within tile
    ushort4 val;
    val.x = ls[(kk + 0) * 72 + n];
    val.y = ls[(kk + 1) * 72 + n];
    val.z = ls[(kk + 2) * 72 + n];
    val.w = ls[(kk + 3) * 72 + n];
    *(ushort4*)(vt + (size_t)(h * 64 + n) * 2048 + t0 + kk) = val;
  }
}

// ------------- MFMA flash attention, split-key 8-way partials ----------
// grid (h=16, 32 qt, 8 chunks); block 256 (4 waves), 64 q-rows per block.
// no-rescale softmax (|score*0.12| <= 0.27): partials combine exactly as
// y = sum_c Z_c * L_c / sum_c L_c. Empty chunks write only L=0 (combine
// skips their Z).
#define ALD 72
__global__ __launch_bounds__(256) void attn_mfma(const u16* __restrict__ qb,
                                                 const u16* __restrict__ kb,
                                                 const u16* __restrict__ vt,
                                                 u16* __restrict__ Zp,
                                                 float* __restrict__ Lp) {
  __shared__ alignas(16) u16 Ks[64 * ALD];        // K tile [key][d]
  __shared__ alignas(16) u16 Vt[64 * ALD];        // V tile [d][key] (pre-transposed src)
  __shared__ alignas(16) u16 Ps[4 * 16 * ALD];    // per-wave P [row][key]
  int h = blockIdx.x;
  int qt = 31 - blockIdx.y;            // heavy q-tiles dispatch first
  int c = blockIdx.z;
  int w8 = (qt + 8) >> 3;              // chunk width = ceil((qt+1)/8) key-tiles
  int jb = c * w8;
  int je = min(jb + w8, qt + 1);
  int slot = (h * 32 + qt) * 8 + c;
  int t0 = qt * 64;
  int tid = threadIdx.x;
  int lane = tid & 63, w = tid >> 6;
  int m16 = lane & 15, q = lane >> 4;
  u16* zout = Zp + (size_t)slot * 4096;
  float* lout = Lp + (size_t)slot * 64;
  if (jb >= je) {                      // empty chunk: zero only its L slot
    if (m16 == 0)
#pragma unroll
      for (int r = 0; r < 4; ++r) lout[w * 16 + q * 4 + r] = 0.f;
    return;
  }
  const u16* qrow = qb + (size_t)(t0 + w * 16 + m16) * 1024 + h * 64;
  bf16x8 qa0 = *(const bf16x8*)(qrow + q * 8);
  bf16x8 qa1 = *(const bf16x8*)(qrow + 32 + q * 8);
  f32x4 Yacc[4] = {};
  float lsum[4] = {0.f, 0.f, 0.f, 0.f};
  int trow = t0 + w * 16 + q * 4;
  int krow_s = tid >> 2, kcol_s = (tid & 3) * 16;   // K staging: 4 thr/row
  int vd_s = tid >> 2, vk_s = (tid & 3) * 16;       // V staging: [d][key] rows
  u16* pw = &Ps[w * 16 * ALD];
  for (int jt = jb; jt < je; ++jt) {
    int j0 = jt * 64;
    const u16* ksrc = kb + (size_t)(j0 + krow_s) * 1024 + h * 64 + kcol_s;
    uint4 kv0 = *(const uint4*)ksrc;
    uint4 kv1 = *(const uint4*)(ksrc + 8);
    const u16* vsrc = vt + (size_t)(h * 64 + vd_s) * 2048 + j0 + vk_s;
    uint4 vv0 = *(const uint4*)vsrc;
    uint4 vv1 = *(const uint4*)(vsrc + 8);
    __syncthreads();   // protect prev-iter LDS reads
    *(uint4*)&Ks[krow_s * ALD + kcol_s] = kv0;
    *(uint4*)&Ks[krow_s * ALD + kcol_s + 8] = kv1;
    *(uint4*)&Vt[vd_s * ALD + vk_s] = vv0;
    *(uint4*)&Vt[vd_s * ALD + vk_s + 8] = vv1;
    __syncthreads();
    // ---- scores: S[m][n] = sum_d Q[m][d] K[j0+n][d]
    f32x4 S[4] = {};
#pragma unroll
    for (int nt = 0; nt < 4; ++nt) {
      bf16x8 b0 = *(const bf16x8*)&Ks[(nt * 16 + m16) * ALD + q * 8];
      bf16x8 b1 = *(const bf16x8*)&Ks[(nt * 16 + m16) * ALD + 32 + q * 8];
      S[nt] = __builtin_amdgcn_mfma_f32_16x16x32_bf16(qa0, b0, S[nt], 0, 0, 0);
      S[nt] = __builtin_amdgcn_mfma_f32_16x16x32_bf16(qa1, b1, S[nt], 0, 0, 0);
    }
    // ---- exp + causal mask, row sums, P -> LDS
    bool diag = (jt == qt);
    float tmp[4] = {0.f, 0.f, 0.f, 0.f};
#pragma unroll
    for (int nt = 0; nt < 4; ++nt) {
      int j = j0 + nt * 16 + m16;
#pragma unroll
      for (int r = 0; r < 4; ++r) {
        float p = __expf(S[nt][r] * 0.12f);
        if (diag && (j > trow + r)) p = 0.f;
        tmp[r] += p;
        pw[(q * 4 + r) * ALD + nt * 16 + m16] = f2bf(p);
      }
    }
#pragma unroll
    for (int r = 0; r < 4; ++r) {
      float s = tmp[r];
      s += __shfl_xor(s, 1); s += __shfl_xor(s, 2);
      s += __shfl_xor(s, 4); s += __shfl_xor(s, 8);
      lsum[r] += s;
    }
    // ---- P C-layout -> A-layout via wave-private LDS (no barrier needed)
    bf16x8 pa0 = *(const bf16x8*)&pw[m16 * ALD + q * 8];
    bf16x8 pa1 = *(const bf16x8*)&pw[m16 * ALD + 32 + q * 8];
    // ---- PV: Y[m][d] += sum_k P[m][k] V[k][d]
#pragma unroll
    for (int nt = 0; nt < 4; ++nt) {
      bf16x8 b0 = *(const bf16x8*)&Vt[(nt * 16 + m16) * ALD + q * 8];
      bf16x8 b1 = *(const bf16x8*)&Vt[(nt * 16 + m16) * ALD + 32 + q * 8];
      Yacc[nt] = __builtin_amdgcn_mfma_f32_16x16x32_bf16(pa0, b0, Yacc[nt], 0, 0, 0);
      Yacc[nt] = __builtin_amdgcn_mfma_f32_16x16x32_bf16(pa1, b1, Yacc[nt], 0, 0, 0);
    }
  }
  // ---- epilogue: Z = Y / L (per-chunk normalized), store Z bf16 + L fp32
#pragma unroll
  for (int r = 0; r < 4; ++r) {
    float inv = __builtin_amdgcn_rcpf(lsum[r]);
#pragma unroll
    for (int nt = 0; nt < 4; ++nt)
      zout[(w * 16 + q * 4 + r) * 64 + nt * 16 + m16] = f2bf(Yacc[nt][r] * inv);
  }
  if (m16 == 0)
#pragma unroll
    for (int r = 0; r < 4; ++r) lout[w * 16 + q * 4 + r] = lsum[r];
}

// ------- combine partials: yb[t][h*64+d] = sum_c Z*L / sum_c L (skip L==0) -------
__global__ __launch_bounds__(256) void combine(const u16* __restrict__ Zp,
                                               const float* __restrict__ Lp,
                                               u16* __restrict__ yb) {
  int tid = threadIdx.x;
  int g = blockIdx.x * 4 + (tid >> 6);   // row id: h*2048 + t
  int d = tid & 63;
  int h = g >> 11, t = g & 2047;
  int qt = t >> 6, r = t & 63;
  int base = (h * 32 + qt) * 8;
  float acc = 0.f, lt = 0.f;
#pragma unroll
  for (int c = 0; c < 8; ++c) {
    float L = Lp[(size_t)(base + c) * 64 + r];
    if (L > 0.f) {                      // wave-uniform (same L across 64 d-lanes)
      float z = bf2f(Zp[(size_t)(base + c) * 4096 + r * 64 + d]);
      acc += z * L;
      lt += L;
    }
  }
  yb[(size_t)t * 1024 + h * 64 + d] = f2bf(acc / lt);
}

extern "C" void kernel_launch(void* const* d_in, const int* in_sizes, int n_in,
                              void* d_out, int out_size, void* d_ws, size_t ws_size,
                              hipStream_t stream) {
  const float* x   = (const float*)d_in[0];
  const float* Wq  = (const float*)d_in[1];
  const float* Wk  = (const float*)d_in[2];
  const float* Wv  = (const float*)d_in[3];
  const float* Wo  = (const float*)d_in[4];
  const float* sqk = (const float*)d_in[5];
  float* out = (float*)d_out;
  char* ws = (char*)d_ws;

  // workspace layout (MB offsets):
  //   0-  4 : xb bf16 x            -> qb16 (xb dead after QKV gemm)
  //   4- 12 : Wt 4x bf16 [n][k]
  //  12- 36 : QKV split-K bf16 partials, 6 x 4MB (q0,q1,k0,k1,v0,v1)
  //  36- 40 : kb16
  //  40- 44 : vt16
  //  44- 76 : Zp (bf16, 4096 slots x 8KB)
  //  76- 77 : Lp
  //  77- 81 : yb
  //  81- 89 : o-proj split-K bf16 partials, 2 x 4MB
  u16*   xb   = (u16*)ws;
  u16*   qb16 = (u16*)ws;
  u16*   Wt   = (u16*)(ws + ((size_t)4 << 20));
  u16*   qkvp = (u16*)(ws + ((size_t)12 << 20));
  u16*   kb16 = (u16*)(ws + ((size_t)36 << 20));
  u16*   vt16 = (u16*)(ws + ((size_t)40 << 20));
  u16*   Zp   = (u16*)(ws + ((size_t)44 << 20));
  float* Lp   = (float*)(ws + ((size_t)76 << 20));
  u16*   yb   = (u16*)(ws + ((size_t)77 << 20));
  u16*   op   = (u16*)(ws + ((size_t)81 << 20));
  u16*   Wto  = Wt + (size_t)3 * 1024 * 1024;

  cast_kernel<<<2048, 256, 0, stream>>>(x, xb, 2048 * 1024);
  transcast<<<dim3(16, 16, 4), 256, 0, stream>>>(Wq, Wk, Wv, Wo, Wt);
  // QKV, split-K=2: z = proj*2 + khalf, 768 blocks, bf16 partials
  gemm128<<<dim3(8, 16, 6), 256, 0, stream>>>(
      xb, Wt, qkvp, 1024, (size_t)1024 * 1024, PS);
  nrv<<<dim3(8192, 3), 256, 0, stream>>>(qkvp, qb16, kb16, vt16, sqk);
  attn_mfma<<<dim3(16, 32, 8), 256, 0, stream>>>(qb16, kb16, vt16, Zp, Lp);
  combine<<<8192, 256, 0, stream>>>(Zp, Lp, yb);
  // o-proj, split-K=2: 256 blocks, bf16 partials, then reduce to fp32
  gemm128<<<dim3(8, 16, 2), 256, 0, stream>>>(yb, Wto, op, 1024, 0, PS);
  addout<<<1024, 256, 0, stream>>>(op, op + PS, out, 2048 * 1024);
}

// Round 6
// 251.974 us; speedup vs baseline: 1.0023x; 1.0023x over previous
//
#include <hip/hip_runtime.h>

typedef unsigned short u16;
typedef unsigned int u32;
typedef __attribute__((ext_vector_type(8))) short bf16x8;
typedef __attribute__((ext_vector_type(4))) float f32x4;

__device__ __forceinline__ u16 f2bf(float x) {
  unsigned u = __float_as_uint(x);
  u += 0x7fffu + ((u >> 16) & 1u);   // RNE
  return (u16)(u >> 16);
}
__device__ __forceinline__ float bf2f(u16 z) {
  return __uint_as_float((u32)z << 16);
}

// ---------------- cast fp32 -> bf16 (RNE); n divisible by 1024 ----------------
__global__ __launch_bounds__(256) void cast_kernel(const float* __restrict__ in,
                                                   u16* __restrict__ out, int n) {
  int i = (blockIdx.x * 256 + threadIdx.x) * 4;
  if (i >= n) return;
  float4 f = *(const float4*)(in + i);
  ushort4 o;
  o.x = f2bf(f.x); o.y = f2bf(f.y); o.z = f2bf(f.z); o.w = f2bf(f.w);
  *(ushort4*)(out + i) = o;
}

// ------------- transpose+cast 4 weights: W[k][n] fp32 -> Wt[n][k] bf16 -------------
__global__ __launch_bounds__(256) void transcast(const float* __restrict__ W0,
                                                 const float* __restrict__ W1,
                                                 const float* __restrict__ W2,
                                                 const float* __restrict__ W3,
                                                 u16* __restrict__ out) {
  __shared__ alignas(16) u16 ls[64 * 72];
  int z = blockIdx.z;
  const float* W = (z == 0) ? W0 : (z == 1) ? W1 : (z == 2) ? W2 : W3;
  u16* o = out + (size_t)z * (1024u * 1024u);
  int kt = blockIdx.y * 64, nt = blockIdx.x * 64;
  int tid = threadIdx.x;
  int r = tid >> 2, c0 = (tid & 3) * 16;
  const float* src = W + (size_t)(kt + r) * 1024 + nt + c0;
  u16 tmp[16];
#pragma unroll
  for (int c = 0; c < 16; c += 4) {
    float4 f = *(const float4*)(src + c);
    tmp[c + 0] = f2bf(f.x); tmp[c + 1] = f2bf(f.y);
    tmp[c + 2] = f2bf(f.z); tmp[c + 3] = f2bf(f.w);
  }
#pragma unroll
  for (int c = 0; c < 16; ++c) ls[r * 72 + c0 + c] = tmp[c];
  __syncthreads();
#pragma unroll
  for (int pass = 0; pass < 4; ++pass) {
    int n = pass * 16 + (tid >> 4);
    int kk = (tid & 15) * 4;
    ushort4 val;
    val.x = ls[(kk + 0) * 72 + n];
    val.y = ls[(kk + 1) * 72 + n];
    val.z = ls[(kk + 2) * 72 + n];
    val.w = ls[(kk + 3) * 72 + n];
    *(ushort4*)(o + (size_t)(nt + n) * 1024 + kt + kk) = val;
  }
}

// ------- bf16 MFMA GEMM 128x128, BK=64, split-K=2: partial bf16 out -------
// grid.z: proj = z>>1 selects B (stride bz); kh = z&1. Cz = C + z*cz (bf16).
// NOTE: no min-waves launch bound — (256,3) clamped VGPRs to 64 and caused
// ~200 MB/dispatch scratch-spill traffic (R5: WRITE_SIZE 221 MB, dur 74 us).
#define GLD 72  // 144B row stride
__global__ __launch_bounds__(256) void gemm128(const u16* __restrict__ A,
                                               const u16* __restrict__ Bmat,
                                               u16* __restrict__ C,
                                               int K, size_t bz, size_t cz) {
  __shared__ alignas(16) u16 As[128 * GLD];
  __shared__ alignas(16) u16 Bs[128 * GLD];
  int z = blockIdx.z;
  const u16* B = Bmat + (size_t)(z >> 1) * bz;
  u16* Cz = C + (size_t)z * cz;
  int kbeg = (z & 1) * 512;
  int tid = threadIdx.x;
  int bm = blockIdx.y * 128, bn = blockIdx.x * 128;
  int lane = tid & 63, w = tid >> 6;
  int wm = (w >> 1) * 64, wn = (w & 1) * 64;
  int m16 = lane & 15, q = lane >> 4;
  f32x4 acc[4][4] = {};
  int srow = tid >> 1, scol = (tid & 1) * 32;
  const u16* aptr = A + (size_t)(bm + srow) * K + scol;
  const u16* bptr = B + (size_t)(bn + srow) * K + scol;
  for (int k0 = kbeg; k0 < kbeg + 512; k0 += 64) {
    uint4 a[4], b[4];
#pragma unroll
    for (int j = 0; j < 4; ++j) {
      a[j] = *(const uint4*)(aptr + k0 + j * 8);
      b[j] = *(const uint4*)(bptr + k0 + j * 8);
    }
    __syncthreads();
#pragma unroll
    for (int j = 0; j < 4; ++j) {
      *(uint4*)&As[srow * GLD + scol + j * 8] = a[j];
      *(uint4*)&Bs[srow * GLD + scol + j * 8] = b[j];
    }
    __syncthreads();
#pragma unroll
    for (int s = 0; s < 2; ++s) {
      bf16x8 af[4], bfr[4];
#pragma unroll
      for (int mt = 0; mt < 4; ++mt)
        af[mt] = *(const bf16x8*)&As[(wm + mt * 16 + m16) * GLD + s * 32 + q * 8];
#pragma unroll
      for (int nt = 0; nt < 4; ++nt)
        bfr[nt] = *(const bf16x8*)&Bs[(wn + nt * 16 + m16) * GLD + s * 32 + q * 8];
#pragma unroll
      for (int mt = 0; mt < 4; ++mt)
#pragma unroll
        for (int nt = 0; nt < 4; ++nt)
          acc[mt][nt] = __builtin_amdgcn_mfma_f32_16x16x32_bf16(af[mt], bfr[nt], acc[mt][nt], 0, 0, 0);
    }
  }
#pragma unroll
  for (int mt = 0; mt < 4; ++mt)
#pragma unroll
    for (int nt = 0; nt < 4; ++nt)
#pragma unroll
      for (int r = 0; r < 4; ++r) {
        int row = bm + wm + mt * 16 + q * 4 + r;
        int col = bn + wn + nt * 16 + m16;
        Cz[(size_t)row * 1024 + col] = f2bf(acc[mt][nt][r]);
      }
}

// ---- out = bf(p0) + bf(p1) (o-proj split-K reduce) -> fp32, 8 elems/thread ----
__global__ __launch_bounds__(256) void addout(const u16* __restrict__ p0,
                                              const u16* __restrict__ p1,
                                              float* __restrict__ out, int n) {
  int i = (blockIdx.x * 256 + threadIdx.x) * 8;
  if (i >= n) return;
  u16 a[8], b[8];
  *(uint4*)a = *(const uint4*)(p0 + i);
  *(uint4*)b = *(const uint4*)(p1 + i);
  float o[8];
#pragma unroll
  for (int j = 0; j < 8; ++j) o[j] = bf2f(a[j]) + bf2f(b[j]);
  *(float4*)(out + i) = *(float4*)&o[0];
  *(float4*)(out + i + 4) = *(float4*)&o[4];
}

// -- fused: y=0 -> q normrope, y=1 -> k normrope, y=2 -> v transpose --
// all read (bf16 partial0 + partial1); p has 6 partials at stride PS.
#define PS ((size_t)2048 * 1024)
__global__ __launch_bounds__(256) void nrv(const u16* __restrict__ p,
                                           u16* __restrict__ qd,
                                           u16* __restrict__ kd,
                                           u16* __restrict__ vt,
                                           const float* __restrict__ s_qk) {
  int tid = threadIdx.x;
  int y = blockIdx.y;
  if (y < 2) {   // ---- normrope on q (y=0) / k (y=1) ----
    const u16* a = p + (size_t)(2 * y) * PS;
    const u16* b = a + PS;
    u16* dst = y ? kd : qd;
    int lane = tid & 63;
    int idx = blockIdx.x * 4 + (tid >> 6);   // t*16 + h
    int t = idx >> 4, h = idx & 15;
    size_t off = (size_t)t * 1024 + h * 64 + lane;
    float x = bf2f(a[off]) + bf2f(b[off]);
    float ss = x * x;
#pragma unroll
    for (int m = 32; m; m >>= 1) ss += __shfl_xor(ss, m);
    float xn = x * rsqrtf(ss + 1e-12f) * (s_qk[h * 64 + lane] * 32.0f);  // sqrt(1024)=32
    float other = __shfl_xor(xn, 32);
    int i = lane & 31;
    float fr = (i < 16) ? exp2f(-10.0f * (float)i / 15.0f) : 0.0f;  // (1/1024)^(i/15)
    float th = (float)t * fr;
    float c = cosf(th), s = sinf(th);
    float sgn = (lane < 32) ? s : -s;  // y1 = x1*c + x2*s ; y2 = x2*c - x1*s
    dst[off] = f2bf(xn * c + other * sgn);
    return;
  }
  // ---- v transpose: vt[h*64+d][t] = bf(v0+v1) ----
  if (blockIdx.x >= 512) return;
  __shared__ alignas(16) u16 ls[64 * 72];
  const u16* v0 = p + 4 * PS;
  const u16* v1 = p + 5 * PS;
  int t0 = (blockIdx.x & 31) * 64, h = blockIdx.x >> 5;
  int r = tid >> 2, c0 = (tid & 3) * 16;
  size_t off = (size_t)(t0 + r) * 1024 + h * 64 + c0;
  u16 ta[16], tb[16];
  *(uint4*)&ta[0] = *(const uint4*)(v0 + off);
  *(uint4*)&ta[8] = *(const uint4*)(v0 + off + 8);
  *(uint4*)&tb[0] = *(const uint4*)(v1 + off);
  *(uint4*)&tb[8] = *(const uint4*)(v1 + off + 8);
#pragma unroll
  for (int c = 0; c < 16; ++c) ls[r * 72 + c0 + c] = f2bf(bf2f(ta[c]) + bf2f(tb[c]));
  __syncthreads();
#pragma unroll
  for (int pass = 0; pass < 4; ++pass) {
    int n = pass * 16 + (tid >> 4);   // d within head
    int kk = (tid & 15) * 4;          // t within tile
    ushort4 val;
    val.x = ls[(kk + 0) * 72 + n];
    val.y = ls[(kk + 1) * 72 + n];
    val.z = ls[(kk + 2) * 72 + n];
    val.w = ls[(kk + 3) * 72 + n];
    *(ushort4*)(vt + (size_t)(h * 64 + n) * 2048 + t0 + kk) = val;
  }
}

// ------------- MFMA flash attention, split-key 8-way partials ----------
// grid (h=16, 32 qt, 8 chunks); block 256 (4 waves), 64 q-rows per block.
// no-rescale softmax (|score*0.12| <= 0.27): partials combine exactly as
// y = sum_c Z_c * L_c / sum_c L_c. Empty chunks write only L=0 (combine
// skips their Z).
#define ALD 72
__global__ __launch_bounds__(256) void attn_mfma(const u16* __restrict__ qb,
                                                 const u16* __restrict__ kb,
                                                 const u16* __restrict__ vt,
                                                 u16* __restrict__ Zp,
                                                 float* __restrict__ Lp) {
  __shared__ alignas(16) u16 Ks[64 * ALD];        // K tile [key][d]
  __shared__ alignas(16) u16 Vt[64 * ALD];        // V tile [d][key] (pre-transposed src)
  __shared__ alignas(16) u16 Ps[4 * 16 * ALD];    // per-wave P [row][key]
  int h = blockIdx.x;
  int qt = 31 - blockIdx.y;            // heavy q-tiles dispatch first
  int c = blockIdx.z;
  int w8 = (qt + 8) >> 3;              // chunk width = ceil((qt+1)/8) key-tiles
  int jb = c * w8;
  int je = min(jb + w8, qt + 1);
  int slot = (h * 32 + qt) * 8 + c;
  int t0 = qt * 64;
  int tid = threadIdx.x;
  int lane = tid & 63, w = tid >> 6;
  int m16 = lane & 15, q = lane >> 4;
  u16* zout = Zp + (size_t)slot * 4096;
  float* lout = Lp + (size_t)slot * 64;
  if (jb >= je) {                      // empty chunk: zero only its L slot
    if (m16 == 0)
#pragma unroll
      for (int r = 0; r < 4; ++r) lout[w * 16 + q * 4 + r] = 0.f;
    return;
  }
  const u16* qrow = qb + (size_t)(t0 + w * 16 + m16) * 1024 + h * 64;
  bf16x8 qa0 = *(const bf16x8*)(qrow + q * 8);
  bf16x8 qa1 = *(const bf16x8*)(qrow + 32 + q * 8);
  f32x4 Yacc[4] = {};
  float lsum[4] = {0.f, 0.f, 0.f, 0.f};
  int trow = t0 + w * 16 + q * 4;
  int krow_s = tid >> 2, kcol_s = (tid & 3) * 16;   // K staging: 4 thr/row
  int vd_s = tid >> 2, vk_s = (tid & 3) * 16;       // V staging: [d][key] rows
  u16* pw = &Ps[w * 16 * ALD];
  for (int jt = jb; jt < je; ++jt) {
    int j0 = jt * 64;
    const u16* ksrc = kb + (size_t)(j0 + krow_s) * 1024 + h * 64 + kcol_s;
    uint4 kv0 = *(const uint4*)ksrc;
    uint4 kv1 = *(const uint4*)(ksrc + 8);
    const u16* vsrc = vt + (size_t)(h * 64 + vd_s) * 2048 + j0 + vk_s;
    uint4 vv0 = *(const uint4*)vsrc;
    uint4 vv1 = *(const uint4*)(vsrc + 8);
    __syncthreads();   // protect prev-iter LDS reads
    *(uint4*)&Ks[krow_s * ALD + kcol_s] = kv0;
    *(uint4*)&Ks[krow_s * ALD + kcol_s + 8] = kv1;
    *(uint4*)&Vt[vd_s * ALD + vk_s] = vv0;
    *(uint4*)&Vt[vd_s * ALD + vk_s + 8] = vv1;
    __syncthreads();
    // ---- scores: S[m][n] = sum_d Q[m][d] K[j0+n][d]
    f32x4 S[4] = {};
#pragma unroll
    for (int nt = 0; nt < 4; ++nt) {
      bf16x8 b0 = *(const bf16x8*)&Ks[(nt * 16 + m16) * ALD + q * 8];
      bf16x8 b1 = *(const bf16x8*)&Ks[(nt * 16 + m16) * ALD + 32 + q * 8];
      S[nt] = __builtin_amdgcn_mfma_f32_16x16x32_bf16(qa0, b0, S[nt], 0, 0, 0);
      S[nt] = __builtin_amdgcn_mfma_f32_16x16x32_bf16(qa1, b1, S[nt], 0, 0, 0);
    }
    // ---- exp + causal mask, row sums, P -> LDS
    bool diag = (jt == qt);
    float tmp[4] = {0.f, 0.f, 0.f, 0.f};
#pragma unroll
    for (int nt = 0; nt < 4; ++nt) {
      int j = j0 + nt * 16 + m16;
#pragma unroll
      for (int r = 0; r < 4; ++r) {
        float p = __expf(S[nt][r] * 0.12f);
        if (diag && (j > trow + r)) p = 0.f;
        tmp[r] += p;
        pw[(q * 4 + r) * ALD + nt * 16 + m16] = f2bf(p);
      }
    }
#pragma unroll
    for (int r = 0; r < 4; ++r) {
      float s = tmp[r];
      s += __shfl_xor(s, 1); s += __shfl_xor(s, 2);
      s += __shfl_xor(s, 4); s += __shfl_xor(s, 8);
      lsum[r] += s;
    }
    // ---- P C-layout -> A-layout via wave-private LDS (no barrier needed)
    bf16x8 pa0 = *(const bf16x8*)&pw[m16 * ALD + q * 8];
    bf16x8 pa1 = *(const bf16x8*)&pw[m16 * ALD + 32 + q * 8];
    // ---- PV: Y[m][d] += sum_k P[m][k] V[k][d]
#pragma unroll
    for (int nt = 0; nt < 4; ++nt) {
      bf16x8 b0 = *(const bf16x8*)&Vt[(nt * 16 + m16) * ALD + q * 8];
      bf16x8 b1 = *(const bf16x8*)&Vt[(nt * 16 + m16) * ALD + 32 + q * 8];
      Yacc[nt] = __builtin_amdgcn_mfma_f32_16x16x32_bf16(pa0, b0, Yacc[nt], 0, 0, 0);
      Yacc[nt] = __builtin_amdgcn_mfma_f32_16x16x32_bf16(pa1, b1, Yacc[nt], 0, 0, 0);
    }
  }
  // ---- epilogue: Z = Y / L (per-chunk normalized), store Z bf16 + L fp32
#pragma unroll
  for (int r = 0; r < 4; ++r) {
    float inv = __builtin_amdgcn_rcpf(lsum[r]);
#pragma unroll
    for (int nt = 0; nt < 4; ++nt)
      zout[(w * 16 + q * 4 + r) * 64 + nt * 16 + m16] = f2bf(Yacc[nt][r] * inv);
  }
  if (m16 == 0)
#pragma unroll
    for (int r = 0; r < 4; ++r) lout[w * 16 + q * 4 + r] = lsum[r];
}

// ------- combine partials: yb[t][h*64+d] = sum_c Z*L / sum_c L (skip L==0) -------
__global__ __launch_bounds__(256) void combine(const u16* __restrict__ Zp,
                                               const float* __restrict__ Lp,
                                               u16* __restrict__ yb) {
  int tid = threadIdx.x;
  int g = blockIdx.x * 4 + (tid >> 6);   // row id: h*2048 + t
  int d = tid & 63;
  int h = g >> 11, t = g & 2047;
  int qt = t >> 6, r = t & 63;
  int base = (h * 32 + qt) * 8;
  float acc = 0.f, lt = 0.f;
#pragma unroll
  for (int c = 0; c < 8; ++c) {
    float L = Lp[(size_t)(base + c) * 64 + r];
    if (L > 0.f) {                      // wave-uniform (same L across 64 d-lanes)
      float z = bf2f(Zp[(size_t)(base + c) * 4096 + r * 64 + d]);
      acc += z * L;
      lt += L;
    }
  }
  yb[(size_t)t * 1024 + h * 64 + d] = f2bf(acc / lt);
}

extern "C" void kernel_launch(void* const* d_in, const int* in_sizes, int n_in,
                              void* d_out, int out_size, void* d_ws, size_t ws_size,
                              hipStream_t stream) {
  const float* x   = (const float*)d_in[0];
  const float* Wq  = (const float*)d_in[1];
  const float* Wk  = (const float*)d_in[2];
  const float* Wv  = (const float*)d_in[3];
  const float* Wo  = (const float*)d_in[4];
  const float* sqk = (const float*)d_in[5];
  float* out = (float*)d_out;
  char* ws = (char*)d_ws;

  // workspace layout (MB offsets):
  //   0-  4 : xb bf16 x            -> qb16 (xb dead after QKV gemm)
  //   4- 12 : Wt 4x bf16 [n][k]
  //  12- 36 : QKV split-K bf16 partials, 6 x 4MB (q0,q1,k0,k1,v0,v1)
  //  36- 40 : kb16
  //  40- 44 : vt16
  //  44- 76 : Zp (bf16, 4096 slots x 8KB)
  //  76- 77 : Lp
  //  77- 81 : yb
  //  81- 89 : o-proj split-K bf16 partials, 2 x 4MB
  u16*   xb   = (u16*)ws;
  u16*   qb16 = (u16*)ws;
  u16*   Wt   = (u16*)(ws + ((size_t)4 << 20));
  u16*   qkvp = (u16*)(ws + ((size_t)12 << 20));
  u16*   kb16 = (u16*)(ws + ((size_t)36 << 20));
  u16*   vt16 = (u16*)(ws + ((size_t)40 << 20));
  u16*   Zp   = (u16*)(ws + ((size_t)44 << 20));
  float* Lp   = (float*)(ws + ((size_t)76 << 20));
  u16*   yb   = (u16*)(ws + ((size_t)77 << 20));
  u16*   op   = (u16*)(ws + ((size_t)81 << 20));
  u16*   Wto  = Wt + (size_t)3 * 1024 * 1024;

  cast_kernel<<<2048, 256, 0, stream>>>(x, xb, 2048 * 1024);
  transcast<<<dim3(16, 16, 4), 256, 0, stream>>>(Wq, Wk, Wv, Wo, Wt);
  // QKV, split-K=2: z = proj*2 + khalf, 768 blocks, bf16 partials
  gemm128<<<dim3(8, 16, 6), 256, 0, stream>>>(
      xb, Wt, qkvp, 1024, (size_t)1024 * 1024, PS);
  nrv<<<dim3(8192, 3), 256, 0, stream>>>(qkvp, qb16, kb16, vt16, sqk);
  attn_mfma<<<dim3(16, 32, 8), 256, 0, stream>>>(qb16, kb16, vt16, Zp, Lp);
  combine<<<8192, 256, 0, stream>>>(Zp, Lp, yb);
  // o-proj, split-K=2: 256 blocks, bf16 partials, then reduce to fp32
  gemm128<<<dim3(8, 16, 2), 256, 0, stream>>>(yb, Wto, op, 1024, 0, PS);
  addout<<<1024, 256, 0, stream>>>(op, op + PS, out, 2048 * 1024);
}

// Round 7
// 194.268 us; speedup vs baseline: 1.3000x; 1.2970x over previous
//
#include <hip/hip_runtime.h>

typedef unsigned short u16;
typedef unsigned int u32;
typedef __attribute__((ext_vector_type(8))) short bf16x8;
typedef __attribute__((ext_vector_type(4))) float f32x4;

__device__ __forceinline__ u16 f2bf(float x) {
  unsigned u = __float_as_uint(x);
  u += 0x7fffu + ((u >> 16) & 1u);   // RNE
  return (u16)(u >> 16);
}
__device__ __forceinline__ float bf2f(u16 z) {
  return __uint_as_float((u32)z << 16);
}

// ---------------- cast fp32 -> bf16 (RNE); n divisible by 1024 ----------------
__global__ __launch_bounds__(256) void cast_kernel(const float* __restrict__ in,
                                                   u16* __restrict__ out, int n) {
  int i = (blockIdx.x * 256 + threadIdx.x) * 4;
  if (i >= n) return;
  float4 f = *(const float4*)(in + i);
  ushort4 o;
  o.x = f2bf(f.x); o.y = f2bf(f.y); o.z = f2bf(f.z); o.w = f2bf(f.w);
  *(ushort4*)(out + i) = o;
}

// ------------- transpose+cast 4 weights: W[k][n] fp32 -> Wt[n][k] bf16 -------------
__global__ __launch_bounds__(256) void transcast(const float* __restrict__ W0,
                                                 const float* __restrict__ W1,
                                                 const float* __restrict__ W2,
                                                 const float* __restrict__ W3,
                                                 u16* __restrict__ out) {
  __shared__ alignas(16) u16 ls[64 * 72];
  int z = blockIdx.z;
  const float* W = (z == 0) ? W0 : (z == 1) ? W1 : (z == 2) ? W2 : W3;
  u16* o = out + (size_t)z * (1024u * 1024u);
  int kt = blockIdx.y * 64, nt = blockIdx.x * 64;
  int tid = threadIdx.x;
  int r = tid >> 2, c0 = (tid & 3) * 16;
  const float* src = W + (size_t)(kt + r) * 1024 + nt + c0;
  u16 tmp[16];
#pragma unroll
  for (int c = 0; c < 16; c += 4) {
    float4 f = *(const float4*)(src + c);
    tmp[c + 0] = f2bf(f.x); tmp[c + 1] = f2bf(f.y);
    tmp[c + 2] = f2bf(f.z); tmp[c + 3] = f2bf(f.w);
  }
#pragma unroll
  for (int c = 0; c < 16; ++c) ls[r * 72 + c0 + c] = tmp[c];
  __syncthreads();
#pragma unroll
  for (int pass = 0; pass < 4; ++pass) {
    int n = pass * 16 + (tid >> 4);
    int kk = (tid & 15) * 4;
    ushort4 val;
    val.x = ls[(kk + 0) * 72 + n];
    val.y = ls[(kk + 1) * 72 + n];
    val.z = ls[(kk + 2) * 72 + n];
    val.w = ls[(kk + 3) * 72 + n];
    *(ushort4*)(o + (size_t)(nt + n) * 1024 + kt + kk) = val;
  }
}

// ------- bf16 MFMA GEMM 128x128, BK=32, split-K=2: fp32 partial out -------
// grid.z: proj = z>>1 selects B (stride bz); kh = z&1. Cz = C + z*cz (fp32).
// R4-proven structure. DO NOT raise BK to 64 or emit bf16 scalar C-stores:
// R5/R6 showed that variant spills staging regs -> ~190 MB/dispatch scratch
// traffic, 75 us/dispatch (WRITE_SIZE 183-221 MB, VGPR clamped 64-80).
#define GLD 40  // LDS stride: rows alias at +8 -> 2-way on banks (free)
#define KH 512
__global__ __launch_bounds__(256) void gemm128(const u16* __restrict__ A,
                                               const u16* __restrict__ Bmat,
                                               float* __restrict__ C,
                                               int K, size_t bz, size_t cz) {
  __shared__ alignas(16) u16 As[128 * GLD];
  __shared__ alignas(16) u16 Bs[128 * GLD];
  int z = blockIdx.z;
  const u16* B = Bmat + (size_t)(z >> 1) * bz;
  float* Cz = C + (size_t)z * cz;
  int kbeg = (z & 1) * KH;
  int tid = threadIdx.x;
  int bm = blockIdx.y * 128, bn = blockIdx.x * 128;
  int lane = tid & 63, w = tid >> 6;
  int wm = (w >> 1) * 64, wn = (w & 1) * 64;
  int m16 = lane & 15, q = lane >> 4;
  f32x4 acc[4][4] = {};
  int srow = tid >> 1, scol = (tid & 1) * 16;
  const u16* aptr = A + (size_t)(bm + srow) * K + scol;
  const u16* bptr = B + (size_t)(bn + srow) * K + scol;
  for (int k0 = kbeg; k0 < kbeg + KH; k0 += 32) {
    uint4 a0 = *(const uint4*)(aptr + k0);
    uint4 a1 = *(const uint4*)(aptr + k0 + 8);
    uint4 b0 = *(const uint4*)(bptr + k0);
    uint4 b1 = *(const uint4*)(bptr + k0 + 8);
    __syncthreads();
    *(uint4*)&As[srow * GLD + scol] = a0;
    *(uint4*)&As[srow * GLD + scol + 8] = a1;
    *(uint4*)&Bs[srow * GLD + scol] = b0;
    *(uint4*)&Bs[srow * GLD + scol + 8] = b1;
    __syncthreads();
    bf16x8 af[4], bfr[4];
#pragma unroll
    for (int mt = 0; mt < 4; ++mt)
      af[mt] = *(const bf16x8*)&As[(wm + mt * 16 + m16) * GLD + q * 8];
#pragma unroll
    for (int nt = 0; nt < 4; ++nt)
      bfr[nt] = *(const bf16x8*)&Bs[(wn + nt * 16 + m16) * GLD + q * 8];
#pragma unroll
    for (int mt = 0; mt < 4; ++mt)
#pragma unroll
      for (int nt = 0; nt < 4; ++nt)
        acc[mt][nt] = __builtin_amdgcn_mfma_f32_16x16x32_bf16(af[mt], bfr[nt], acc[mt][nt], 0, 0, 0);
  }
#pragma unroll
  for (int mt = 0; mt < 4; ++mt)
#pragma unroll
    for (int nt = 0; nt < 4; ++nt)
#pragma unroll
      for (int r = 0; r < 4; ++r) {
        int row = bm + wm + mt * 16 + q * 4 + r;
        int col = bn + wn + nt * 16 + m16;
        Cz[(size_t)row * 1024 + col] = acc[mt][nt][r];
      }
}

// ---- out = p0 + p1 (o-proj split-K reduce), fp32, n div by 1024 ----
__global__ __launch_bounds__(256) void addout(const float* __restrict__ p0,
                                              const float* __restrict__ p1,
                                              float* __restrict__ out, int n) {
  int i = (blockIdx.x * 256 + threadIdx.x) * 4;
  if (i >= n) return;
  float4 a = *(const float4*)(p0 + i);
  float4 b = *(const float4*)(p1 + i);
  float4 o = {a.x + b.x, a.y + b.y, a.z + b.z, a.w + b.w};
  *(float4*)(out + i) = o;
}

// -- fused: y=0 -> q normrope, y=1 -> k normrope, y=2 -> v transpose --
// all read (fp32 partial0 + partial1); p has 6 partials at stride PSF floats.
#define PSF ((size_t)2048 * 1024)
__global__ __launch_bounds__(256) void nrv(const float* __restrict__ p,
                                           u16* __restrict__ qd,
                                           u16* __restrict__ kd,
                                           u16* __restrict__ vt,
                                           const float* __restrict__ s_qk) {
  int tid = threadIdx.x;
  int y = blockIdx.y;
  if (y < 2) {   // ---- normrope on q (y=0) / k (y=1) ----
    const float* a = p + (size_t)(2 * y) * PSF;
    const float* b = a + PSF;
    u16* dst = y ? kd : qd;
    int lane = tid & 63;
    int idx = blockIdx.x * 4 + (tid >> 6);   // t*16 + h
    int t = idx >> 4, h = idx & 15;
    size_t off = (size_t)t * 1024 + h * 64 + lane;
    float x = a[off] + b[off];
    float ss = x * x;
#pragma unroll
    for (int m = 32; m; m >>= 1) ss += __shfl_xor(ss, m);
    float xn = x * rsqrtf(ss + 1e-12f) * (s_qk[h * 64 + lane] * 32.0f);  // sqrt(1024)=32
    float other = __shfl_xor(xn, 32);
    int i = lane & 31;
    float fr = (i < 16) ? exp2f(-10.0f * (float)i / 15.0f) : 0.0f;  // (1/1024)^(i/15)
    float th = (float)t * fr;
    float c = cosf(th), s = sinf(th);
    float sgn = (lane < 32) ? s : -s;  // y1 = x1*c + x2*s ; y2 = x2*c - x1*s
    dst[off] = f2bf(xn * c + other * sgn);
    return;
  }
  // ---- v transpose: vt[h*64+d][t] = bf(v0+v1) ----
  if (blockIdx.x >= 512) return;
  __shared__ alignas(16) u16 ls[64 * 72];
  const float* v0 = p + 4 * PSF;
  const float* v1 = p + 5 * PSF;
  int t0 = (blockIdx.x & 31) * 64, h = blockIdx.x >> 5;
  int r = tid >> 2, c0 = (tid & 3) * 16;
  size_t off = (size_t)(t0 + r) * 1024 + h * 64 + c0;
  u16 tmp[16];
#pragma unroll
  for (int c = 0; c < 16; c += 4) {
    float4 fa = *(const float4*)(v0 + off + c);
    float4 fb = *(const float4*)(v1 + off + c);
    tmp[c + 0] = f2bf(fa.x + fb.x); tmp[c + 1] = f2bf(fa.y + fb.y);
    tmp[c + 2] = f2bf(fa.z + fb.z); tmp[c + 3] = f2bf(fa.w + fb.w);
  }
#pragma unroll
  for (int c = 0; c < 16; ++c) ls[r * 72 + c0 + c] = tmp[c];
  __syncthreads();
#pragma unroll
  for (int pass = 0; pass < 4; ++pass) {
    int n = pass * 16 + (tid >> 4);   // d within head
    int kk = (tid & 15) * 4;          // t within tile
    ushort4 val;
    val.x = ls[(kk + 0) * 72 + n];
    val.y = ls[(kk + 1) * 72 + n];
    val.z = ls[(kk + 2) * 72 + n];
    val.w = ls[(kk + 3) * 72 + n];
    *(ushort4*)(vt + (size_t)(h * 64 + n) * 2048 + t0 + kk) = val;
  }
}

// ------------- MFMA flash attention, split-key 8-way partials ----------
// grid (h=16, 32 qt, 8 chunks); block 256 (4 waves), 64 q-rows per block.
// no-rescale softmax (|score*0.12| <= 0.27): partials combine exactly as
// y = sum_c Z_c * L_c / sum_c L_c. Empty chunks write only L=0 (combine
// skips their Z).
#define ALD 72
__global__ __launch_bounds__(256) void attn_mfma(const u16* __restrict__ qb,
                                                 const u16* __restrict__ kb,
                                                 const u16* __restrict__ vt,
                                                 u16* __restrict__ Zp,
                                                 float* __restrict__ Lp) {
  __shared__ alignas(16) u16 Ks[64 * ALD];        // K tile [key][d]
  __shared__ alignas(16) u16 Vt[64 * ALD];        // V tile [d][key] (pre-transposed src)
  __shared__ alignas(16) u16 Ps[4 * 16 * ALD];    // per-wave P [row][key]
  int h = blockIdx.x;
  int qt = 31 - blockIdx.y;            // heavy q-tiles dispatch first
  int c = blockIdx.z;
  int w8 = (qt + 8) >> 3;              // chunk width = ceil((qt+1)/8) key-tiles
  int jb = c * w8;
  int je = min(jb + w8, qt + 1);
  int slot = (h * 32 + qt) * 8 + c;
  int t0 = qt * 64;
  int tid = threadIdx.x;
  int lane = tid & 63, w = tid >> 6;
  int m16 = lane & 15, q = lane >> 4;
  u16* zout = Zp + (size_t)slot * 4096;
  float* lout = Lp + (size_t)slot * 64;
  if (jb >= je) {                      // empty chunk: zero only its L slot
    if (m16 == 0)
#pragma unroll
      for (int r = 0; r < 4; ++r) lout[w * 16 + q * 4 + r] = 0.f;
    return;
  }
  const u16* qrow = qb + (size_t)(t0 + w * 16 + m16) * 1024 + h * 64;
  bf16x8 qa0 = *(const bf16x8*)(qrow + q * 8);
  bf16x8 qa1 = *(const bf16x8*)(qrow + 32 + q * 8);
  f32x4 Yacc[4] = {};
  float lsum[4] = {0.f, 0.f, 0.f, 0.f};
  int trow = t0 + w * 16 + q * 4;
  int krow_s = tid >> 2, kcol_s = (tid & 3) * 16;   // K staging: 4 thr/row
  int vd_s = tid >> 2, vk_s = (tid & 3) * 16;       // V staging: [d][key] rows
  u16* pw = &Ps[w * 16 * ALD];
  for (int jt = jb; jt < je; ++jt) {
    int j0 = jt * 64;
    const u16* ksrc = kb + (size_t)(j0 + krow_s) * 1024 + h * 64 + kcol_s;
    uint4 kv0 = *(const uint4*)ksrc;
    uint4 kv1 = *(const uint4*)(ksrc + 8);
    const u16* vsrc = vt + (size_t)(h * 64 + vd_s) * 2048 + j0 + vk_s;
    uint4 vv0 = *(const uint4*)vsrc;
    uint4 vv1 = *(const uint4*)(vsrc + 8);
    __syncthreads();   // protect prev-iter LDS reads
    *(uint4*)&Ks[krow_s * ALD + kcol_s] = kv0;
    *(uint4*)&Ks[krow_s * ALD + kcol_s + 8] = kv1;
    *(uint4*)&Vt[vd_s * ALD + vk_s] = vv0;
    *(uint4*)&Vt[vd_s * ALD + vk_s + 8] = vv1;
    __syncthreads();
    // ---- scores: S[m][n] = sum_d Q[m][d] K[j0+n][d]
    f32x4 S[4] = {};
#pragma unroll
    for (int nt = 0; nt < 4; ++nt) {
      bf16x8 b0 = *(const bf16x8*)&Ks[(nt * 16 + m16) * ALD + q * 8];
      bf16x8 b1 = *(const bf16x8*)&Ks[(nt * 16 + m16) * ALD + 32 + q * 8];
      S[nt] = __builtin_amdgcn_mfma_f32_16x16x32_bf16(qa0, b0, S[nt], 0, 0, 0);
      S[nt] = __builtin_amdgcn_mfma_f32_16x16x32_bf16(qa1, b1, S[nt], 0, 0, 0);
    }
    // ---- exp + causal mask, row sums, P -> LDS
    bool diag = (jt == qt);
    float tmp[4] = {0.f, 0.f, 0.f, 0.f};
#pragma unroll
    for (int nt = 0; nt < 4; ++nt) {
      int j = j0 + nt * 16 + m16;
#pragma unroll
      for (int r = 0; r < 4; ++r) {
        float p = __expf(S[nt][r] * 0.12f);
        if (diag && (j > trow + r)) p = 0.f;
        tmp[r] += p;
        pw[(q * 4 + r) * ALD + nt * 16 + m16] = f2bf(p);
      }
    }
#pragma unroll
    for (int r = 0; r < 4; ++r) {
      float s = tmp[r];
      s += __shfl_xor(s, 1); s += __shfl_xor(s, 2);
      s += __shfl_xor(s, 4); s += __shfl_xor(s, 8);
      lsum[r] += s;
    }
    // ---- P C-layout -> A-layout via wave-private LDS (no barrier needed)
    bf16x8 pa0 = *(const bf16x8*)&pw[m16 * ALD + q * 8];
    bf16x8 pa1 = *(const bf16x8*)&pw[m16 * ALD + 32 + q * 8];
    // ---- PV: Y[m][d] += sum_k P[m][k] V[k][d]
#pragma unroll
    for (int nt = 0; nt < 4; ++nt) {
      bf16x8 b0 = *(const bf16x8*)&Vt[(nt * 16 + m16) * ALD + q * 8];
      bf16x8 b1 = *(const bf16x8*)&Vt[(nt * 16 + m16) * ALD + 32 + q * 8];
      Yacc[nt] = __builtin_amdgcn_mfma_f32_16x16x32_bf16(pa0, b0, Yacc[nt], 0, 0, 0);
      Yacc[nt] = __builtin_amdgcn_mfma_f32_16x16x32_bf16(pa1, b1, Yacc[nt], 0, 0, 0);
    }
  }
  // ---- epilogue: Z = Y / L (per-chunk normalized), store Z bf16 + L fp32
#pragma unroll
  for (int r = 0; r < 4; ++r) {
    float inv = __builtin_amdgcn_rcpf(lsum[r]);
#pragma unroll
    for (int nt = 0; nt < 4; ++nt)
      zout[(w * 16 + q * 4 + r) * 64 + nt * 16 + m16] = f2bf(Yacc[nt][r] * inv);
  }
  if (m16 == 0)
#pragma unroll
    for (int r = 0; r < 4; ++r) lout[w * 16 + q * 4 + r] = lsum[r];
}

// ------- combine partials: yb[t][h*64+d] = sum_c Z*L / sum_c L (skip L==0) -------
__global__ __launch_bounds__(256) void combine(const u16* __restrict__ Zp,
                                               const float* __restrict__ Lp,
                                               u16* __restrict__ yb) {
  int tid = threadIdx.x;
  int g = blockIdx.x * 4 + (tid >> 6);   // row id: h*2048 + t
  int d = tid & 63;
  int h = g >> 11, t = g & 2047;
  int qt = t >> 6, r = t & 63;
  int base = (h * 32 + qt) * 8;
  float acc = 0.f, lt = 0.f;
#pragma unroll
  for (int c = 0; c < 8; ++c) {
    float L = Lp[(size_t)(base + c) * 64 + r];
    if (L > 0.f) {                      // wave-uniform (same L across 64 d-lanes)
      float z = bf2f(Zp[(size_t)(base + c) * 4096 + r * 64 + d]);
      acc += z * L;
      lt += L;
    }
  }
  yb[(size_t)t * 1024 + h * 64 + d] = f2bf(acc / lt);
}

extern "C" void kernel_launch(void* const* d_in, const int* in_sizes, int n_in,
                              void* d_out, int out_size, void* d_ws, size_t ws_size,
                              hipStream_t stream) {
  const float* x   = (const float*)d_in[0];
  const float* Wq  = (const float*)d_in[1];
  const float* Wk  = (const float*)d_in[2];
  const float* Wv  = (const float*)d_in[3];
  const float* Wo  = (const float*)d_in[4];
  const float* sqk = (const float*)d_in[5];
  float* out = (float*)d_out;
  char* ws = (char*)d_ws;

  // workspace layout (MB offsets; ws is 256 MiB):
  //   0-  4 : xb bf16 x           -> qb16 (xb dead after QKV gemm)
  //   4- 12 : Wt 4x bf16 [n][k]
  //  12- 60 : QKV split-K fp32 partials, 6 x 8MB (q0,q1,k0,k1,v0,v1)
  //  60- 64 : kb16
  //  64- 68 : vt16
  //  68-100 : Zp (bf16, 4096 slots x 8KB)
  // 100-101 : Lp
  // 101-105 : yb
  // 105-121 : o-proj split-K fp32 partials, 2 x 8MB
  u16*   xb   = (u16*)ws;
  u16*   qb16 = (u16*)ws;
  u16*   Wt   = (u16*)(ws + ((size_t)4 << 20));
  float* qkvp = (float*)(ws + ((size_t)12 << 20));
  u16*   kb16 = (u16*)(ws + ((size_t)60 << 20));
  u16*   vt16 = (u16*)(ws + ((size_t)64 << 20));
  u16*   Zp   = (u16*)(ws + ((size_t)68 << 20));
  float* Lp   = (float*)(ws + ((size_t)100 << 20));
  u16*   yb   = (u16*)(ws + ((size_t)101 << 20));
  float* op   = (float*)(ws + ((size_t)105 << 20));
  u16*   Wto  = Wt + (size_t)3 * 1024 * 1024;

  cast_kernel<<<2048, 256, 0, stream>>>(x, xb, 2048 * 1024);
  transcast<<<dim3(16, 16, 4), 256, 0, stream>>>(Wq, Wk, Wv, Wo, Wt);
  // QKV, split-K=2: z = proj*2 + khalf, 768 blocks, fp32 partials
  gemm128<<<dim3(8, 16, 6), 256, 0, stream>>>(
      xb, Wt, qkvp, 1024, (size_t)1024 * 1024, PSF);
  nrv<<<dim3(8192, 3), 256, 0, stream>>>(qkvp, qb16, kb16, vt16, sqk);
  attn_mfma<<<dim3(16, 32, 8), 256, 0, stream>>>(qb16, kb16, vt16, Zp, Lp);
  combine<<<8192, 256, 0, stream>>>(Zp, Lp, yb);
  // o-proj, split-K=2: 256 blocks, fp32 partials, then reduce
  gemm128<<<dim3(8, 16, 2), 256, 0, stream>>>(yb, Wto, op, 1024, 0, PSF);
  addout<<<2048, 256, 0, stream>>>(op, op + PSF, out, 2048 * 1024);
}

// Round 8
// 191.708 us; speedup vs baseline: 1.3174x; 1.0134x over previous
//
#include <hip/hip_runtime.h>

typedef unsigned short u16;
typedef unsigned int u32;
typedef __attribute__((ext_vector_type(8))) short bf16x8;
typedef __attribute__((ext_vector_type(4))) float f32x4;

__device__ __forceinline__ u16 f2bf(float x) {
  unsigned u = __float_as_uint(x);
  u += 0x7fffu + ((u >> 16) & 1u);   // RNE
  return (u16)(u >> 16);
}
__device__ __forceinline__ float bf2f(u16 z) {
  return __uint_as_float((u32)z << 16);
}

// async global->LDS, 16B per lane; LDS dest = wave-uniform base + lane*16
__device__ __forceinline__ void gload16(const u16* g, u16* l) {
  __builtin_amdgcn_global_load_lds(
      (__attribute__((address_space(1))) void*)g,
      (__attribute__((address_space(3))) void*)l, 16, 0, 0);
}

// ---------------- cast fp32 -> bf16 (RNE); n divisible by 1024 ----------------
__global__ __launch_bounds__(256) void cast_kernel(const float* __restrict__ in,
                                                   u16* __restrict__ out, int n) {
  int i = (blockIdx.x * 256 + threadIdx.x) * 4;
  if (i >= n) return;
  float4 f = *(const float4*)(in + i);
  ushort4 o;
  o.x = f2bf(f.x); o.y = f2bf(f.y); o.z = f2bf(f.z); o.w = f2bf(f.w);
  *(ushort4*)(out + i) = o;
}

// ------------- transpose+cast 4 weights: W[k][n] fp32 -> Wt[n][k] bf16 -------------
__global__ __launch_bounds__(256) void transcast(const float* __restrict__ W0,
                                                 const float* __restrict__ W1,
                                                 const float* __restrict__ W2,
                                                 const float* __restrict__ W3,
                                                 u16* __restrict__ out) {
  __shared__ alignas(16) u16 ls[64 * 72];
  int z = blockIdx.z;
  const float* W = (z == 0) ? W0 : (z == 1) ? W1 : (z == 2) ? W2 : W3;
  u16* o = out + (size_t)z * (1024u * 1024u);
  int kt = blockIdx.y * 64, nt = blockIdx.x * 64;
  int tid = threadIdx.x;
  int r = tid >> 2, c0 = (tid & 3) * 16;
  const float* src = W + (size_t)(kt + r) * 1024 + nt + c0;
  u16 tmp[16];
#pragma unroll
  for (int c = 0; c < 16; c += 4) {
    float4 f = *(const float4*)(src + c);
    tmp[c + 0] = f2bf(f.x); tmp[c + 1] = f2bf(f.y);
    tmp[c + 2] = f2bf(f.z); tmp[c + 3] = f2bf(f.w);
  }
#pragma unroll
  for (int c = 0; c < 16; ++c) ls[r * 72 + c0 + c] = tmp[c];
  __syncthreads();
#pragma unroll
  for (int pass = 0; pass < 4; ++pass) {
    int n = pass * 16 + (tid >> 4);
    int kk = (tid & 15) * 4;
    ushort4 val;
    val.x = ls[(kk + 0) * 72 + n];
    val.y = ls[(kk + 1) * 72 + n];
    val.z = ls[(kk + 2) * 72 + n];
    val.w = ls[(kk + 3) * 72 + n];
    *(ushort4*)(o + (size_t)(nt + n) * 1024 + kt + kk) = val;
  }
}

// ------- bf16 MFMA GEMM 128x128, BK=32, split-K=2: fp32 partial out -------
// m97-style staging: global_load_lds width=16, linear 64B rows, XOR col
// swizzle (phys chunk = logical ^ (row&3)) -> conflict-free b128 frag reads
// (8 lanes/bank-quad uniform). No register staging (R5/R6 lesson: staging
// regs spill -> 200 MB scratch traffic). fp32 C out (bf16 scalar stores bad).
__global__ __launch_bounds__(256) void gemm128(const u16* __restrict__ A,
                                               const u16* __restrict__ Bmat,
                                               float* __restrict__ C,
                                               int K, size_t bz, size_t cz) {
  __shared__ alignas(16) u16 As[128 * 32];
  __shared__ alignas(16) u16 Bs[128 * 32];
  int z = blockIdx.z;
  const u16* B = Bmat + (size_t)(z >> 1) * bz;
  float* Cz = C + (size_t)z * cz;
  int kbeg = (z & 1) * 512;
  int tid = threadIdx.x;
  int bm = blockIdx.y * 128, bn = blockIdx.x * 128;
  int lane = tid & 63, w = tid >> 6;
  int wm = (w >> 1) * 64, wn = (w & 1) * 64;
  int m16 = lane & 15, q = lane >> 4;
  f32x4 acc[4][4] = {};
  // staging addresses: issue j of wave w covers rows w*32 + j*16 .. +16
  int srow = lane >> 2;                         // 0..15 within issue
  int schunk = (lane & 3) ^ (srow & 3);         // logical 8-elem chunk (XOR)
  const u16* ag0 = A + (size_t)(bm + w * 32 + srow) * K + kbeg + schunk * 8;
  const u16* ag1 = ag0 + (size_t)16 * K;
  const u16* bg0 = B + (size_t)(bn + w * 32 + srow) * K + kbeg + schunk * 8;
  const u16* bg1 = bg0 + (size_t)16 * K;
  u16* al0 = &As[w * 1024];
  u16* al1 = &As[w * 1024 + 512];
  u16* bl0 = &Bs[w * 1024];
  u16* bl1 = &Bs[w * 1024 + 512];
  for (int k0 = 0; k0 < 512; k0 += 32) {
    __syncthreads();                 // prev tile's frag reads done
    gload16(ag0 + k0, al0);
    gload16(ag1 + k0, al1);
    gload16(bg0 + k0, bl0);
    gload16(bg1 + k0, bl1);
    __syncthreads();                 // vmcnt(0) drain: tile resident
    bf16x8 af[4], bfr[4];
#pragma unroll
    for (int mt = 0; mt < 4; ++mt) {
      int rr = wm + mt * 16 + m16;
      af[mt] = *(const bf16x8*)&As[rr * 32 + (q ^ (rr & 3)) * 8];
    }
#pragma unroll
    for (int nt = 0; nt < 4; ++nt) {
      int rr = wn + nt * 16 + m16;
      bfr[nt] = *(const bf16x8*)&Bs[rr * 32 + (q ^ (rr & 3)) * 8];
    }
#pragma unroll
    for (int mt = 0; mt < 4; ++mt)
#pragma unroll
      for (int nt = 0; nt < 4; ++nt)
        acc[mt][nt] = __builtin_amdgcn_mfma_f32_16x16x32_bf16(af[mt], bfr[nt], acc[mt][nt], 0, 0, 0);
  }
#pragma unroll
  for (int mt = 0; mt < 4; ++mt)
#pragma unroll
    for (int nt = 0; nt < 4; ++nt)
#pragma unroll
      for (int r = 0; r < 4; ++r) {
        int row = bm + wm + mt * 16 + q * 4 + r;
        int col = bn + wn + nt * 16 + m16;
        Cz[(size_t)row * 1024 + col] = acc[mt][nt][r];
      }
}

// ---- out = p0 + p1 (o-proj split-K reduce), fp32, n div by 1024 ----
__global__ __launch_bounds__(256) void addout(const float* __restrict__ p0,
                                              const float* __restrict__ p1,
                                              float* __restrict__ out, int n) {
  int i = (blockIdx.x * 256 + threadIdx.x) * 4;
  if (i >= n) return;
  float4 a = *(const float4*)(p0 + i);
  float4 b = *(const float4*)(p1 + i);
  float4 o = {a.x + b.x, a.y + b.y, a.z + b.z, a.w + b.w};
  *(float4*)(out + i) = o;
}

// -- fused: y=0 -> q normrope, y=1 -> k normrope, y=2 -> v transpose --
// all read (fp32 partial0 + partial1); p has 6 partials at stride PSF floats.
#define PSF ((size_t)2048 * 1024)
__global__ __launch_bounds__(256) void nrv(const float* __restrict__ p,
                                           u16* __restrict__ qd,
                                           u16* __restrict__ kd,
                                           u16* __restrict__ vt,
                                           const float* __restrict__ s_qk) {
  int tid = threadIdx.x;
  int y = blockIdx.y;
  if (y < 2) {   // ---- normrope on q (y=0) / k (y=1) ----
    const float* a = p + (size_t)(2 * y) * PSF;
    const float* b = a + PSF;
    u16* dst = y ? kd : qd;
    int lane = tid & 63;
    int idx = blockIdx.x * 4 + (tid >> 6);   // t*16 + h
    int t = idx >> 4, h = idx & 15;
    size_t off = (size_t)t * 1024 + h * 64 + lane;
    float x = a[off] + b[off];
    float ss = x * x;
#pragma unroll
    for (int m = 32; m; m >>= 1) ss += __shfl_xor(ss, m);
    float xn = x * rsqrtf(ss + 1e-12f) * (s_qk[h * 64 + lane] * 32.0f);  // sqrt(1024)=32
    float other = __shfl_xor(xn, 32);
    int i = lane & 31;
    float fr = (i < 16) ? exp2f(-10.0f * (float)i / 15.0f) : 0.0f;  // (1/1024)^(i/15)
    float th = (float)t * fr;
    float c = cosf(th), s = sinf(th);
    float sgn = (lane < 32) ? s : -s;  // y1 = x1*c + x2*s ; y2 = x2*c - x1*s
    dst[off] = f2bf(xn * c + other * sgn);
    return;
  }
  // ---- v transpose: vt[h*64+d][t] = bf(v0+v1) ----
  if (blockIdx.x >= 512) return;
  __shared__ alignas(16) u16 ls[64 * 72];
  const float* v0 = p + 4 * PSF;
  const float* v1 = p + 5 * PSF;
  int t0 = (blockIdx.x & 31) * 64, h = blockIdx.x >> 5;
  int r = tid >> 2, c0 = (tid & 3) * 16;
  size_t off = (size_t)(t0 + r) * 1024 + h * 64 + c0;
  u16 tmp[16];
#pragma unroll
  for (int c = 0; c < 16; c += 4) {
    float4 fa = *(const float4*)(v0 + off + c);
    float4 fb = *(const float4*)(v1 + off + c);
    tmp[c + 0] = f2bf(fa.x + fb.x); tmp[c + 1] = f2bf(fa.y + fb.y);
    tmp[c + 2] = f2bf(fa.z + fb.z); tmp[c + 3] = f2bf(fa.w + fb.w);
  }
#pragma unroll
  for (int c = 0; c < 16; ++c) ls[r * 72 + c0 + c] = tmp[c];
  __syncthreads();
#pragma unroll
  for (int pass = 0; pass < 4; ++pass) {
    int n = pass * 16 + (tid >> 4);   // d within head
    int kk = (tid & 15) * 4;          // t within tile
    ushort4 val;
    val.x = ls[(kk + 0) * 72 + n];
    val.y = ls[(kk + 1) * 72 + n];
    val.z = ls[(kk + 2) * 72 + n];
    val.w = ls[(kk + 3) * 72 + n];
    *(ushort4*)(vt + (size_t)(h * 64 + n) * 2048 + t0 + kk) = val;
  }
}

// ------------- MFMA flash attention, split-key 4-way partials ----------
// grid (h=16, 32 qt, 4 chunks); block 256 (4 waves), 64 q-rows per block.
// 4 chunks proven faster than 8 (R4 180 vs R7 194: Zp traffic + block
// overhead). no-rescale softmax (|score*0.12| <= 0.27): partials combine as
// y = sum_c Z_c * L_c / sum_c L_c. Empty chunks write only L=0.
#define ALD 72
__global__ __launch_bounds__(256) void attn_mfma(const u16* __restrict__ qb,
                                                 const u16* __restrict__ kb,
                                                 const u16* __restrict__ vt,
                                                 u16* __restrict__ Zp,
                                                 float* __restrict__ Lp) {
  __shared__ alignas(16) u16 Ks[64 * ALD];        // K tile [key][d]
  __shared__ alignas(16) u16 Vt[64 * ALD];        // V tile [d][key] (pre-transposed src)
  __shared__ alignas(16) u16 Ps[4 * 16 * ALD];    // per-wave P [row][key]
  int h = blockIdx.x;
  int qt = 31 - blockIdx.y;            // heavy q-tiles dispatch first
  int c = blockIdx.z;
  int w4 = (qt + 4) >> 2;              // chunk width = ceil((qt+1)/4) key-tiles
  int jb = c * w4;
  int je = min(jb + w4, qt + 1);
  int slot = (h * 32 + qt) * 4 + c;
  int t0 = qt * 64;
  int tid = threadIdx.x;
  int lane = tid & 63, w = tid >> 6;
  int m16 = lane & 15, q = lane >> 4;
  u16* zout = Zp + (size_t)slot * 4096;
  float* lout = Lp + (size_t)slot * 64;
  if (jb >= je) {                      // empty chunk: zero only its L slot
    if (m16 == 0)
#pragma unroll
      for (int r = 0; r < 4; ++r) lout[w * 16 + q * 4 + r] = 0.f;
    return;
  }
  const u16* qrow = qb + (size_t)(t0 + w * 16 + m16) * 1024 + h * 64;
  bf16x8 qa0 = *(const bf16x8*)(qrow + q * 8);
  bf16x8 qa1 = *(const bf16x8*)(qrow + 32 + q * 8);
  f32x4 Yacc[4] = {};
  float lsum[4] = {0.f, 0.f, 0.f, 0.f};
  int trow = t0 + w * 16 + q * 4;
  int krow_s = tid >> 2, kcol_s = (tid & 3) * 16;   // K staging: 4 thr/row
  int vd_s = tid >> 2, vk_s = (tid & 3) * 16;       // V staging: [d][key] rows
  u16* pw = &Ps[w * 16 * ALD];
  for (int jt = jb; jt < je; ++jt) {
    int j0 = jt * 64;
    const u16* ksrc = kb + (size_t)(j0 + krow_s) * 1024 + h * 64 + kcol_s;
    uint4 kv0 = *(const uint4*)ksrc;
    uint4 kv1 = *(const uint4*)(ksrc + 8);
    const u16* vsrc = vt + (size_t)(h * 64 + vd_s) * 2048 + j0 + vk_s;
    uint4 vv0 = *(const uint4*)vsrc;
    uint4 vv1 = *(const uint4*)(vsrc + 8);
    __syncthreads();   // protect prev-iter LDS reads
    *(uint4*)&Ks[krow_s * ALD + kcol_s] = kv0;
    *(uint4*)&Ks[krow_s * ALD + kcol_s + 8] = kv1;
    *(uint4*)&Vt[vd_s * ALD + vk_s] = vv0;
    *(uint4*)&Vt[vd_s * ALD + vk_s + 8] = vv1;
    __syncthreads();
    // ---- scores: S[m][n] = sum_d Q[m][d] K[j0+n][d]
    f32x4 S[4] = {};
#pragma unroll
    for (int nt = 0; nt < 4; ++nt) {
      bf16x8 b0 = *(const bf16x8*)&Ks[(nt * 16 + m16) * ALD + q * 8];
      bf16x8 b1 = *(const bf16x8*)&Ks[(nt * 16 + m16) * ALD + 32 + q * 8];
      S[nt] = __builtin_amdgcn_mfma_f32_16x16x32_bf16(qa0, b0, S[nt], 0, 0, 0);
      S[nt] = __builtin_amdgcn_mfma_f32_16x16x32_bf16(qa1, b1, S[nt], 0, 0, 0);
    }
    // ---- exp + causal mask, row sums, P -> LDS
    bool diag = (jt == qt);
    float tmp[4] = {0.f, 0.f, 0.f, 0.f};
#pragma unroll
    for (int nt = 0; nt < 4; ++nt) {
      int j = j0 + nt * 16 + m16;
#pragma unroll
      for (int r = 0; r < 4; ++r) {
        float p = __expf(S[nt][r] * 0.12f);
        if (diag && (j > trow + r)) p = 0.f;
        tmp[r] += p;
        pw[(q * 4 + r) * ALD + nt * 16 + m16] = f2bf(p);
      }
    }
#pragma unroll
    for (int r = 0; r < 4; ++r) {
      float s = tmp[r];
      s += __shfl_xor(s, 1); s += __shfl_xor(s, 2);
      s += __shfl_xor(s, 4); s += __shfl_xor(s, 8);
      lsum[r] += s;
    }
    // ---- P C-layout -> A-layout via wave-private LDS (no barrier needed)
    bf16x8 pa0 = *(const bf16x8*)&pw[m16 * ALD + q * 8];
    bf16x8 pa1 = *(const bf16x8*)&pw[m16 * ALD + 32 + q * 8];
    // ---- PV: Y[m][d] += sum_k P[m][k] V[k][d]
#pragma unroll
    for (int nt = 0; nt < 4; ++nt) {
      bf16x8 b0 = *(const bf16x8*)&Vt[(nt * 16 + m16) * ALD + q * 8];
      bf16x8 b1 = *(const bf16x8*)&Vt[(nt * 16 + m16) * ALD + 32 + q * 8];
      Yacc[nt] = __builtin_amdgcn_mfma_f32_16x16x32_bf16(pa0, b0, Yacc[nt], 0, 0, 0);
      Yacc[nt] = __builtin_amdgcn_mfma_f32_16x16x32_bf16(pa1, b1, Yacc[nt], 0, 0, 0);
    }
  }
  // ---- epilogue: Z = Y / L (per-chunk normalized), store Z bf16 + L fp32
#pragma unroll
  for (int r = 0; r < 4; ++r) {
    float inv = __builtin_amdgcn_rcpf(lsum[r]);
#pragma unroll
    for (int nt = 0; nt < 4; ++nt)
      zout[(w * 16 + q * 4 + r) * 64 + nt * 16 + m16] = f2bf(Yacc[nt][r] * inv);
  }
  if (m16 == 0)
#pragma unroll
    for (int r = 0; r < 4; ++r) lout[w * 16 + q * 4 + r] = lsum[r];
}

// ------- combine partials: yb[t][h*64+d] = sum_c Z*L / sum_c L (skip L==0) -------
__global__ __launch_bounds__(256) void combine(const u16* __restrict__ Zp,
                                               const float* __restrict__ Lp,
                                               u16* __restrict__ yb) {
  int tid = threadIdx.x;
  int g = blockIdx.x * 4 + (tid >> 6);   // row id: h*2048 + t
  int d = tid & 63;
  int h = g >> 11, t = g & 2047;
  int qt = t >> 6, r = t & 63;
  int base = (h * 32 + qt) * 4;
  float acc = 0.f, lt = 0.f;
#pragma unroll
  for (int c = 0; c < 4; ++c) {
    float L = Lp[(size_t)(base + c) * 64 + r];
    if (L > 0.f) {                      // wave-uniform (same L across 64 d-lanes)
      float z = bf2f(Zp[(size_t)(base + c) * 4096 + r * 64 + d]);
      acc += z * L;
      lt += L;
    }
  }
  yb[(size_t)t * 1024 + h * 64 + d] = f2bf(acc / lt);
}

extern "C" void kernel_launch(void* const* d_in, const int* in_sizes, int n_in,
                              void* d_out, int out_size, void* d_ws, size_t ws_size,
                              hipStream_t stream) {
  const float* x   = (const float*)d_in[0];
  const float* Wq  = (const float*)d_in[1];
  const float* Wk  = (const float*)d_in[2];
  const float* Wv  = (const float*)d_in[3];
  const float* Wo  = (const float*)d_in[4];
  const float* sqk = (const float*)d_in[5];
  float* out = (float*)d_out;
  char* ws = (char*)d_ws;

  // workspace layout (MB offsets; ws is 256 MiB):
  //   0-  4 : xb bf16 x           -> qb16 (xb dead after QKV gemm)
  //   4- 12 : Wt 4x bf16 [n][k]
  //  12- 60 : QKV split-K fp32 partials, 6 x 8MB (q0,q1,k0,k1,v0,v1)
  //  60- 64 : kb16
  //  64- 68 : vt16
  //  68- 84 : Zp (bf16, 2048 slots x 8KB)
  //  84- 85 : Lp
  //  85- 89 : yb
  //  89-105 : o-proj split-K fp32 partials, 2 x 8MB
  u16*   xb   = (u16*)ws;
  u16*   qb16 = (u16*)ws;
  u16*   Wt   = (u16*)(ws + ((size_t)4 << 20));
  float* qkvp = (float*)(ws + ((size_t)12 << 20));
  u16*   kb16 = (u16*)(ws + ((size_t)60 << 20));
  u16*   vt16 = (u16*)(ws + ((size_t)64 << 20));
  u16*   Zp   = (u16*)(ws + ((size_t)68 << 20));
  float* Lp   = (float*)(ws + ((size_t)84 << 20));
  u16*   yb   = (u16*)(ws + ((size_t)85 << 20));
  float* op   = (float*)(ws + ((size_t)89 << 20));
  u16*   Wto  = Wt + (size_t)3 * 1024 * 1024;

  cast_kernel<<<2048, 256, 0, stream>>>(x, xb, 2048 * 1024);
  transcast<<<dim3(16, 16, 4), 256, 0, stream>>>(Wq, Wk, Wv, Wo, Wt);
  // QKV, split-K=2: z = proj*2 + khalf, 768 blocks, fp32 partials
  gemm128<<<dim3(8, 16, 6), 256, 0, stream>>>(
      xb, Wt, qkvp, 1024, (size_t)1024 * 1024, PSF);
  nrv<<<dim3(8192, 3), 256, 0, stream>>>(qkvp, qb16, kb16, vt16, sqk);
  attn_mfma<<<dim3(16, 32, 4), 256, 0, stream>>>(qb16, kb16, vt16, Zp, Lp);
  combine<<<8192, 256, 0, stream>>>(Zp, Lp, yb);
  // o-proj, split-K=2: 256 blocks, fp32 partials, then reduce
  gemm128<<<dim3(8, 16, 2), 256, 0, stream>>>(yb, Wto, op, 1024, 0, PSF);
  addout<<<2048, 256, 0, stream>>>(op, op + PSF, out, 2048 * 1024);
}

// Round 9
// 185.354 us; speedup vs baseline: 1.3625x; 1.0343x over previous
//
#include <hip/hip_runtime.h>

typedef unsigned short u16;
typedef unsigned int u32;
typedef __attribute__((ext_vector_type(8))) short bf16x8;
typedef __attribute__((ext_vector_type(4))) float f32x4;

__device__ __forceinline__ u16 f2bf(float x) {
  unsigned u = __float_as_uint(x);
  u += 0x7fffu + ((u >> 16) & 1u);   // RNE
  return (u16)(u >> 16);
}
__device__ __forceinline__ float bf2f(u16 z) {
  return __uint_as_float((u32)z << 16);
}

// ---------------- cast fp32 -> bf16 (RNE); n divisible by 1024 ----------------
__global__ __launch_bounds__(256) void cast_kernel(const float* __restrict__ in,
                                                   u16* __restrict__ out, int n) {
  int i = (blockIdx.x * 256 + threadIdx.x) * 4;
  if (i >= n) return;
  float4 f = *(const float4*)(in + i);
  ushort4 o;
  o.x = f2bf(f.x); o.y = f2bf(f.y); o.z = f2bf(f.z); o.w = f2bf(f.w);
  *(ushort4*)(out + i) = o;
}

// ------------- transpose+cast 4 weights: W[k][n] fp32 -> Wt[n][k] bf16 -------------
__global__ __launch_bounds__(256) void transcast(const float* __restrict__ W0,
                                                 const float* __restrict__ W1,
                                                 const float* __restrict__ W2,
                                                 const float* __restrict__ W3,
                                                 u16* __restrict__ out) {
  __shared__ alignas(16) u16 ls[64 * 72];
  int z = blockIdx.z;
  const float* W = (z == 0) ? W0 : (z == 1) ? W1 : (z == 2) ? W2 : W3;
  u16* o = out + (size_t)z * (1024u * 1024u);
  int kt = blockIdx.y * 64, nt = blockIdx.x * 64;
  int tid = threadIdx.x;
  int r = tid >> 2, c0 = (tid & 3) * 16;
  const float* src = W + (size_t)(kt + r) * 1024 + nt + c0;
  u16 tmp[16];
#pragma unroll
  for (int c = 0; c < 16; c += 4) {
    float4 f = *(const float4*)(src + c);
    tmp[c + 0] = f2bf(f.x); tmp[c + 1] = f2bf(f.y);
    tmp[c + 2] = f2bf(f.z); tmp[c + 3] = f2bf(f.w);
  }
#pragma unroll
  for (int c = 0; c < 16; ++c) ls[r * 72 + c0 + c] = tmp[c];
  __syncthreads();
#pragma unroll
  for (int pass = 0; pass < 4; ++pass) {
    int n = pass * 16 + (tid >> 4);
    int kk = (tid & 15) * 4;
    ushort4 val;
    val.x = ls[(kk + 0) * 72 + n];
    val.y = ls[(kk + 1) * 72 + n];
    val.z = ls[(kk + 2) * 72 + n];
    val.w = ls[(kk + 3) * 72 + n];
    *(ushort4*)(o + (size_t)(nt + n) * 1024 + kt + kk) = val;
  }
}

// ------- bf16 MFMA GEMM 128x128, BK=32, split-K=2: fp32 partial out -------
// grid.z: proj = z>>1 selects B (stride bz); kh = z&1. Cz = C + z*cz (fp32).
// R4-proven register-staged structure. Register staging is load-bearing: the
// compiler issues next-tile global loads during current-tile MFMAs (implicit
// pipelining). Verified regressions to avoid:
//  - BK=64 / bf16 scalar C-stores: staging-reg spill, ~200 MB scratch/dispatch
//    (R5/R6: WRITE_SIZE 183-221 MB, 75 us).
//  - global_load_lds staging: vmcnt(0) drain per 16 MFMAs, no cross-iter
//    overlap at K=512 -> ~+11 us (R8).
#define GLD 40  // LDS stride: rows alias at +8 -> 2-way on banks (free)
#define KH 512
__global__ __launch_bounds__(256) void gemm128(const u16* __restrict__ A,
                                               const u16* __restrict__ Bmat,
                                               float* __restrict__ C,
                                               int K, size_t bz, size_t cz) {
  __shared__ alignas(16) u16 As[128 * GLD];
  __shared__ alignas(16) u16 Bs[128 * GLD];
  int z = blockIdx.z;
  const u16* B = Bmat + (size_t)(z >> 1) * bz;
  float* Cz = C + (size_t)z * cz;
  int kbeg = (z & 1) * KH;
  int tid = threadIdx.x;
  int bm = blockIdx.y * 128, bn = blockIdx.x * 128;
  int lane = tid & 63, w = tid >> 6;
  int wm = (w >> 1) * 64, wn = (w & 1) * 64;
  int m16 = lane & 15, q = lane >> 4;
  f32x4 acc[4][4] = {};
  int srow = tid >> 1, scol = (tid & 1) * 16;
  const u16* aptr = A + (size_t)(bm + srow) * K + scol;
  const u16* bptr = B + (size_t)(bn + srow) * K + scol;
  for (int k0 = kbeg; k0 < kbeg + KH; k0 += 32) {
    uint4 a0 = *(const uint4*)(aptr + k0);
    uint4 a1 = *(const uint4*)(aptr + k0 + 8);
    uint4 b0 = *(const uint4*)(bptr + k0);
    uint4 b1 = *(const uint4*)(bptr + k0 + 8);
    __syncthreads();
    *(uint4*)&As[srow * GLD + scol] = a0;
    *(uint4*)&As[srow * GLD + scol + 8] = a1;
    *(uint4*)&Bs[srow * GLD + scol] = b0;
    *(uint4*)&Bs[srow * GLD + scol + 8] = b1;
    __syncthreads();
    bf16x8 af[4], bfr[4];
#pragma unroll
    for (int mt = 0; mt < 4; ++mt)
      af[mt] = *(const bf16x8*)&As[(wm + mt * 16 + m16) * GLD + q * 8];
#pragma unroll
    for (int nt = 0; nt < 4; ++nt)
      bfr[nt] = *(const bf16x8*)&Bs[(wn + nt * 16 + m16) * GLD + q * 8];
#pragma unroll
    for (int mt = 0; mt < 4; ++mt)
#pragma unroll
      for (int nt = 0; nt < 4; ++nt)
        acc[mt][nt] = __builtin_amdgcn_mfma_f32_16x16x32_bf16(af[mt], bfr[nt], acc[mt][nt], 0, 0, 0);
  }
#pragma unroll
  for (int mt = 0; mt < 4; ++mt)
#pragma unroll
    for (int nt = 0; nt < 4; ++nt)
#pragma unroll
      for (int r = 0; r < 4; ++r) {
        int row = bm + wm + mt * 16 + q * 4 + r;
        int col = bn + wn + nt * 16 + m16;
        Cz[(size_t)row * 1024 + col] = acc[mt][nt][r];
      }
}

// ---- out = p0 + p1 (o-proj split-K reduce), fp32, n div by 1024 ----
__global__ __launch_bounds__(256) void addout(const float* __restrict__ p0,
                                              const float* __restrict__ p1,
                                              float* __restrict__ out, int n) {
  int i = (blockIdx.x * 256 + threadIdx.x) * 4;
  if (i >= n) return;
  float4 a = *(const float4*)(p0 + i);
  float4 b = *(const float4*)(p1 + i);
  float4 o = {a.x + b.x, a.y + b.y, a.z + b.z, a.w + b.w};
  *(float4*)(out + i) = o;
}

// -- fused: y=0 -> q normrope, y=1 -> k normrope, y=2 -> v transpose --
// all read (fp32 partial0 + partial1); p has 6 partials at stride PSF floats.
#define PSF ((size_t)2048 * 1024)
__global__ __launch_bounds__(256) void nrv(const float* __restrict__ p,
                                           u16* __restrict__ qd,
                                           u16* __restrict__ kd,
                                           u16* __restrict__ vt,
                                           const float* __restrict__ s_qk) {
  int tid = threadIdx.x;
  int y = blockIdx.y;
  if (y < 2) {   // ---- normrope on q (y=0) / k (y=1) ----
    const float* a = p + (size_t)(2 * y) * PSF;
    const float* b = a + PSF;
    u16* dst = y ? kd : qd;
    int lane = tid & 63;
    int idx = blockIdx.x * 4 + (tid >> 6);   // t*16 + h
    int t = idx >> 4, h = idx & 15;
    size_t off = (size_t)t * 1024 + h * 64 + lane;
    float x = a[off] + b[off];
    float ss = x * x;
#pragma unroll
    for (int m = 32; m; m >>= 1) ss += __shfl_xor(ss, m);
    float xn = x * rsqrtf(ss + 1e-12f) * (s_qk[h * 64 + lane] * 32.0f);  // sqrt(1024)=32
    float other = __shfl_xor(xn, 32);
    int i = lane & 31;
    float fr = (i < 16) ? exp2f(-10.0f * (float)i / 15.0f) : 0.0f;  // (1/1024)^(i/15)
    float th = (float)t * fr;
    float c = cosf(th), s = sinf(th);
    float sgn = (lane < 32) ? s : -s;  // y1 = x1*c + x2*s ; y2 = x2*c - x1*s
    dst[off] = f2bf(xn * c + other * sgn);
    return;
  }
  // ---- v transpose: vt[h*64+d][t] = bf(v0+v1) ----
  if (blockIdx.x >= 512) return;
  __shared__ alignas(16) u16 ls[64 * 72];
  const float* v0 = p + 4 * PSF;
  const float* v1 = p + 5 * PSF;
  int t0 = (blockIdx.x & 31) * 64, h = blockIdx.x >> 5;
  int r = tid >> 2, c0 = (tid & 3) * 16;
  size_t off = (size_t)(t0 + r) * 1024 + h * 64 + c0;
  u16 tmp[16];
#pragma unroll
  for (int c = 0; c < 16; c += 4) {
    float4 fa = *(const float4*)(v0 + off + c);
    float4 fb = *(const float4*)(v1 + off + c);
    tmp[c + 0] = f2bf(fa.x + fb.x); tmp[c + 1] = f2bf(fa.y + fb.y);
    tmp[c + 2] = f2bf(fa.z + fb.z); tmp[c + 3] = f2bf(fa.w + fb.w);
  }
#pragma unroll
  for (int c = 0; c < 16; ++c) ls[r * 72 + c0 + c] = tmp[c];
  __syncthreads();
#pragma unroll
  for (int pass = 0; pass < 4; ++pass) {
    int n = pass * 16 + (tid >> 4);   // d within head
    int kk = (tid & 15) * 4;          // t within tile
    ushort4 val;
    val.x = ls[(kk + 0) * 72 + n];
    val.y = ls[(kk + 1) * 72 + n];
    val.z = ls[(kk + 2) * 72 + n];
    val.w = ls[(kk + 3) * 72 + n];
    *(ushort4*)(vt + (size_t)(h * 64 + n) * 2048 + t0 + kk) = val;
  }
}

// ------------- MFMA flash attention, split-key 4-way partials ----------
// grid (h=16, 32 qt, 4 chunks); block 256 (4 waves), 64 q-rows per block.
// 4 chunks proven faster than 8 (R4 180 vs R7 194: Zp traffic + block
// overhead). no-rescale softmax (|score*0.12| <= 0.27): partials combine as
// y = sum_c Z_c * L_c / sum_c L_c. Empty chunks write only L=0.
#define ALD 72
__global__ __launch_bounds__(256) void attn_mfma(const u16* __restrict__ qb,
                                                 const u16* __restrict__ kb,
                                                 const u16* __restrict__ vt,
                                                 u16* __restrict__ Zp,
                                                 float* __restrict__ Lp) {
  __shared__ alignas(16) u16 Ks[64 * ALD];        // K tile [key][d]
  __shared__ alignas(16) u16 Vt[64 * ALD];        // V tile [d][key] (pre-transposed src)
  __shared__ alignas(16) u16 Ps[4 * 16 * ALD];    // per-wave P [row][key]
  int h = blockIdx.x;
  int qt = 31 - blockIdx.y;            // heavy q-tiles dispatch first
  int c = blockIdx.z;
  int w4 = (qt + 4) >> 2;              // chunk width = ceil((qt+1)/4) key-tiles
  int jb = c * w4;
  int je = min(jb + w4, qt + 1);
  int slot = (h * 32 + qt) * 4 + c;
  int t0 = qt * 64;
  int tid = threadIdx.x;
  int lane = tid & 63, w = tid >> 6;
  int m16 = lane & 15, q = lane >> 4;
  u16* zout = Zp + (size_t)slot * 4096;
  float* lout = Lp + (size_t)slot * 64;
  if (jb >= je) {                      // empty chunk: zero only its L slot
    if (m16 == 0)
#pragma unroll
      for (int r = 0; r < 4; ++r) lout[w * 16 + q * 4 + r] = 0.f;
    return;
  }
  const u16* qrow = qb + (size_t)(t0 + w * 16 + m16) * 1024 + h * 64;
  bf16x8 qa0 = *(const bf16x8*)(qrow + q * 8);
  bf16x8 qa1 = *(const bf16x8*)(qrow + 32 + q * 8);
  f32x4 Yacc[4] = {};
  float lsum[4] = {0.f, 0.f, 0.f, 0.f};
  int trow = t0 + w * 16 + q * 4;
  int krow_s = tid >> 2, kcol_s = (tid & 3) * 16;   // K staging: 4 thr/row
  int vd_s = tid >> 2, vk_s = (tid & 3) * 16;       // V staging: [d][key] rows
  u16* pw = &Ps[w * 16 * ALD];
  for (int jt = jb; jt < je; ++jt) {
    int j0 = jt * 64;
    const u16* ksrc = kb + (size_t)(j0 + krow_s) * 1024 + h * 64 + kcol_s;
    uint4 kv0 = *(const uint4*)ksrc;
    uint4 kv1 = *(const uint4*)(ksrc + 8);
    const u16* vsrc = vt + (size_t)(h * 64 + vd_s) * 2048 + j0 + vk_s;
    uint4 vv0 = *(const uint4*)vsrc;
    uint4 vv1 = *(const uint4*)(vsrc + 8);
    __syncthreads();   // protect prev-iter LDS reads
    *(uint4*)&Ks[krow_s * ALD + kcol_s] = kv0;
    *(uint4*)&Ks[krow_s * ALD + kcol_s + 8] = kv1;
    *(uint4*)&Vt[vd_s * ALD + vk_s] = vv0;
    *(uint4*)&Vt[vd_s * ALD + vk_s + 8] = vv1;
    __syncthreads();
    // ---- scores: S[m][n] = sum_d Q[m][d] K[j0+n][d]
    f32x4 S[4] = {};
#pragma unroll
    for (int nt = 0; nt < 4; ++nt) {
      bf16x8 b0 = *(const bf16x8*)&Ks[(nt * 16 + m16) * ALD + q * 8];
      bf16x8 b1 = *(const bf16x8*)&Ks[(nt * 16 + m16) * ALD + 32 + q * 8];
      S[nt] = __builtin_amdgcn_mfma_f32_16x16x32_bf16(qa0, b0, S[nt], 0, 0, 0);
      S[nt] = __builtin_amdgcn_mfma_f32_16x16x32_bf16(qa1, b1, S[nt], 0, 0, 0);
    }
    // ---- exp + causal mask, row sums, P -> LDS
    bool diag = (jt == qt);
    float tmp[4] = {0.f, 0.f, 0.f, 0.f};
#pragma unroll
    for (int nt = 0; nt < 4; ++nt) {
      int j = j0 + nt * 16 + m16;
#pragma unroll
      for (int r = 0; r < 4; ++r) {
        float p = __expf(S[nt][r] * 0.12f);
        if (diag && (j > trow + r)) p = 0.f;
        tmp[r] += p;
        pw[(q * 4 + r) * ALD + nt * 16 + m16] = f2bf(p);
      }
    }
#pragma unroll
    for (int r = 0; r < 4; ++r) {
      float s = tmp[r];
      s += __shfl_xor(s, 1); s += __shfl_xor(s, 2);
      s += __shfl_xor(s, 4); s += __shfl_xor(s, 8);
      lsum[r] += s;
    }
    // ---- P C-layout -> A-layout via wave-private LDS (no barrier needed)
    bf16x8 pa0 = *(const bf16x8*)&pw[m16 * ALD + q * 8];
    bf16x8 pa1 = *(const bf16x8*)&pw[m16 * ALD + 32 + q * 8];
    // ---- PV: Y[m][d] += sum_k P[m][k] V[k][d]
#pragma unroll
    for (int nt = 0; nt < 4; ++nt) {
      bf16x8 b0 = *(const bf16x8*)&Vt[(nt * 16 + m16) * ALD + q * 8];
      bf16x8 b1 = *(const bf16x8*)&Vt[(nt * 16 + m16) * ALD + 32 + q * 8];
      Yacc[nt] = __builtin_amdgcn_mfma_f32_16x16x32_bf16(pa0, b0, Yacc[nt], 0, 0, 0);
      Yacc[nt] = __builtin_amdgcn_mfma_f32_16x16x32_bf16(pa1, b1, Yacc[nt], 0, 0, 0);
    }
  }
  // ---- epilogue: Z = Y / L (per-chunk normalized), store Z bf16 + L fp32
#pragma unroll
  for (int r = 0; r < 4; ++r) {
    float inv = __builtin_amdgcn_rcpf(lsum[r]);
#pragma unroll
    for (int nt = 0; nt < 4; ++nt)
      zout[(w * 16 + q * 4 + r) * 64 + nt * 16 + m16] = f2bf(Yacc[nt][r] * inv);
  }
  if (m16 == 0)
#pragma unroll
    for (int r = 0; r < 4; ++r) lout[w * 16 + q * 4 + r] = lsum[r];
}

// ------- combine partials: yb[t][h*64+d] = sum_c Z*L / sum_c L (skip L==0) -------
__global__ __launch_bounds__(256) void combine(const u16* __restrict__ Zp,
                                               const float* __restrict__ Lp,
                                               u16* __restrict__ yb) {
  int tid = threadIdx.x;
  int g = blockIdx.x * 4 + (tid >> 6);   // row id: h*2048 + t
  int d = tid & 63;
  int h = g >> 11, t = g & 2047;
  int qt = t >> 6, r = t & 63;
  int base = (h * 32 + qt) * 4;
  float acc = 0.f, lt = 0.f;
#pragma unroll
  for (int c = 0; c < 4; ++c) {
    float L = Lp[(size_t)(base + c) * 64 + r];
    if (L > 0.f) {                      // wave-uniform (same L across 64 d-lanes)
      float z = bf2f(Zp[(size_t)(base + c) * 4096 + r * 64 + d]);
      acc += z * L;
      lt += L;
    }
  }
  yb[(size_t)t * 1024 + h * 64 + d] = f2bf(acc / lt);
}

extern "C" void kernel_launch(void* const* d_in, const int* in_sizes, int n_in,
                              void* d_out, int out_size, void* d_ws, size_t ws_size,
                              hipStream_t stream) {
  const float* x   = (const float*)d_in[0];
  const float* Wq  = (const float*)d_in[1];
  const float* Wk  = (const float*)d_in[2];
  const float* Wv  = (const float*)d_in[3];
  const float* Wo  = (const float*)d_in[4];
  const float* sqk = (const float*)d_in[5];
  float* out = (float*)d_out;
  char* ws = (char*)d_ws;

  // workspace layout (MB offsets; ws is 256 MiB):
  //   0-  4 : xb bf16 x           -> qb16 (xb dead after QKV gemm)
  //   4- 12 : Wt 4x bf16 [n][k]
  //  12- 60 : QKV split-K fp32 partials, 6 x 8MB (q0,q1,k0,k1,v0,v1)
  //  60- 64 : kb16
  //  64- 68 : vt16
  //  68- 84 : Zp (bf16, 2048 slots x 8KB)
  //  84- 85 : Lp
  //  85- 89 : yb
  //  89-105 : o-proj split-K fp32 partials, 2 x 8MB
  u16*   xb   = (u16*)ws;
  u16*   qb16 = (u16*)ws;
  u16*   Wt   = (u16*)(ws + ((size_t)4 << 20));
  float* qkvp = (float*)(ws + ((size_t)12 << 20));
  u16*   kb16 = (u16*)(ws + ((size_t)60 << 20));
  u16*   vt16 = (u16*)(ws + ((size_t)64 << 20));
  u16*   Zp   = (u16*)(ws + ((size_t)68 << 20));
  float* Lp   = (float*)(ws + ((size_t)84 << 20));
  u16*   yb   = (u16*)(ws + ((size_t)85 << 20));
  float* op   = (float*)(ws + ((size_t)89 << 20));
  u16*   Wto  = Wt + (size_t)3 * 1024 * 1024;

  cast_kernel<<<2048, 256, 0, stream>>>(x, xb, 2048 * 1024);
  transcast<<<dim3(16, 16, 4), 256, 0, stream>>>(Wq, Wk, Wv, Wo, Wt);
  // QKV, split-K=2: z = proj*2 + khalf, 768 blocks, fp32 partials
  gemm128<<<dim3(8, 16, 6), 256, 0, stream>>>(
      xb, Wt, qkvp, 1024, (size_t)1024 * 1024, PSF);
  nrv<<<dim3(8192, 3), 256, 0, stream>>>(qkvp, qb16, kb16, vt16, sqk);
  attn_mfma<<<dim3(16, 32, 4), 256, 0, stream>>>(qb16, kb16, vt16, Zp, Lp);
  combine<<<8192, 256, 0, stream>>>(Zp, Lp, yb);
  // o-proj, split-K=2: 256 blocks, fp32 partials, then reduce
  gemm128<<<dim3(8, 16, 2), 256, 0, stream>>>(yb, Wto, op, 1024, 0, PSF);
  addout<<<2048, 256, 0, stream>>>(op, op + PSF, out, 2048 * 1024);
}